// Round 1
// baseline (15696.609 us; speedup 1.0000x reference)
//
#include <hip/hip_runtime.h>
#include <hip/hip_bf16.h>

// GRU decoder: B=64, T=512, H=1024
// Phase 0: convert enc -> bf16 [T,B,H], W_ih/W_hh -> bf16
// Phase 1: x_proj[t*B+b, g] = sum_h enc[b,t,h]*W_ih[g,h] + b_ih[g]  (bf16 MFMA GEMM)
// Phase 2: 512 sequential step kernels (double-buffered h), gates fused.

typedef short bf16x8 __attribute__((ext_vector_type(8)));
typedef float f32x4 __attribute__((ext_vector_type(4)));

#define NB 64
#define NT 512
#define NH 1024
#define NG 3072  // 3*NH

static __device__ __forceinline__ float bf2f(unsigned short u) {
    unsigned int x = ((unsigned int)u) << 16;
    float f;
    __builtin_memcpy(&f, &x, sizeof(f));
    return f;
}
static __device__ __forceinline__ unsigned short f2bf(float f) {
    unsigned int x;
    __builtin_memcpy(&x, &f, sizeof(x));
    x += 0x7fffu + ((x >> 16) & 1u);  // round-to-nearest-even
    return (unsigned short)(x >> 16);
}

static __device__ __forceinline__ f32x4 mfma16(bf16x8 a, bf16x8 b, f32x4 c) {
    return __builtin_amdgcn_mfma_f32_16x16x32_bf16(a, b, c, 0, 0, 0);
}

__global__ void k_fill_sentinel(float* __restrict__ o, long n) {
    long i = (long)blockIdx.x * blockDim.x + threadIdx.x;
    if (i < n) o[i] = 12345.0f;
}

__global__ void k_convert(const float* __restrict__ in, unsigned short* __restrict__ o, int n) {
    int i = blockIdx.x * blockDim.x + threadIdx.x;
    if (i < n) o[i] = f2bf(in[i]);
}

// enc [B,T,H] f32 -> enc_t [T,B,H] bf16
__global__ void k_convert_enc(const float* __restrict__ enc, unsigned short* __restrict__ o) {
    long i = (long)blockIdx.x * blockDim.x + threadIdx.x;
    if (i >= (long)NB * NT * NH) return;
    int h = (int)(i % NH);
    long bt = i / NH;
    int t = (int)(bt % NT);
    int b = (int)(bt / NT);
    o[((long)t * NB + b) * NH + h] = f2bf(enc[i]);
}

__global__ void k_zero_h(float* __restrict__ hf, unsigned short* __restrict__ hb) {
    int i = blockIdx.x * blockDim.x + threadIdx.x;
    if (i < NB * NH) { hf[i] = 0.0f; hb[i] = 0; }
}

// Phase 1 GEMM: XP[m, n] = sum_k X[m,k]*W[n,k] + bias[n], m over T*B, n over 3H.
// Block = 256 threads = 4 waves arranged 2(M)x2(N); block tile 64(M) x 128(N).
// Wave tile 32x64 = 2x4 fragments of 16x16, K-step 32.
__global__ __launch_bounds__(256) void k_xproj(
    const unsigned short* __restrict__ X,   // [T*B, H] bf16
    const unsigned short* __restrict__ W,   // [3H, H] bf16
    const float* __restrict__ bias,         // [3H]
    unsigned short* __restrict__ XP)        // [T*B, 3H] bf16
{
    const int lane = threadIdx.x & 63;
    const int wv   = threadIdx.x >> 6;
    const int l16  = lane & 15;
    const int lq   = lane >> 4;
    const int n0   = blockIdx.x * 128 + (wv & 1) * 64;
    const int m0   = blockIdx.y * 64 + (wv >> 1) * 32;

    f32x4 acc[2][4];
#pragma unroll
    for (int a = 0; a < 2; ++a)
#pragma unroll
        for (int b = 0; b < 4; ++b) acc[a][b] = (f32x4){0.f, 0.f, 0.f, 0.f};

    for (int k0 = 0; k0 < NH; k0 += 32) {
        bf16x8 af[2];
#pragma unroll
        for (int mi = 0; mi < 2; ++mi)
            af[mi] = *(const bf16x8*)(X + (long)(m0 + mi * 16 + l16) * NH + k0 + lq * 8);
#pragma unroll
        for (int nj = 0; nj < 4; ++nj) {
            bf16x8 bfr = *(const bf16x8*)(W + (long)(n0 + nj * 16 + l16) * NH + k0 + lq * 8);
#pragma unroll
            for (int mi = 0; mi < 2; ++mi)
                acc[mi][nj] = mfma16(af[mi], bfr, acc[mi][nj]);
        }
    }

#pragma unroll
    for (int nj = 0; nj < 4; ++nj) {
        int n = n0 + nj * 16 + l16;
        float bv = bias[n];
#pragma unroll
        for (int mi = 0; mi < 2; ++mi) {
#pragma unroll
            for (int i = 0; i < 4; ++i) {
                int m = m0 + mi * 16 + lq * 4 + i;
                XP[(long)m * NG + n] = f2bf(acc[mi][nj][i] + bv);
            }
        }
    }
}

// Phase 2 step: h_proj = h @ Whh^T + b_hh; gates; h_new. One launch per t.
// 32 blocks x 256 threads = 128 waves. Wave: batch tile m0 = 16*(wv), unit tile
// u0 = 32*blockIdx.x. Computes r,z,n fragments for 16 batch x 32 units.
__global__ __launch_bounds__(256) void k_step(
    const unsigned short* __restrict__ Whh,   // [3H, H] bf16
    const float* __restrict__ bhh,            // [3H]
    const unsigned short* __restrict__ XP,    // [T*B, 3H] bf16
    const unsigned short* __restrict__ hb_cur,// [B, H] bf16
    const float* __restrict__ hf_cur,         // [B, H] f32
    unsigned short* __restrict__ hb_nxt,
    float* __restrict__ hf_nxt,
    float* __restrict__ out,                  // [B, T, H] f32
    int t)
{
    const int lane = threadIdx.x & 63;
    const int wv   = threadIdx.x >> 6;
    const int l16  = lane & 15;
    const int lq   = lane >> 4;
    const int m0   = wv * 16;            // batch tile (4 waves x 16 = 64)
    const int u0   = blockIdx.x * 32;    // unit tile (32 blocks x 32 = 1024)

    f32x4 acc[3][2];
#pragma unroll
    for (int g = 0; g < 3; ++g)
#pragma unroll
        for (int f = 0; f < 2; ++f) acc[g][f] = (f32x4){0.f, 0.f, 0.f, 0.f};

    for (int k0 = 0; k0 < NH; k0 += 32) {
        bf16x8 af = *(const bf16x8*)(hb_cur + (long)(m0 + l16) * NH + k0 + lq * 8);
#pragma unroll
        for (int g = 0; g < 3; ++g) {
#pragma unroll
            for (int f = 0; f < 2; ++f) {
                int row = g * NH + u0 + f * 16 + l16;
                bf16x8 bfr = *(const bf16x8*)(Whh + (long)row * NH + k0 + lq * 8);
                acc[g][f] = mfma16(af, bfr, acc[g][f]);
            }
        }
    }

#pragma unroll
    for (int f = 0; f < 2; ++f) {
        int u = u0 + f * 16 + l16;
        float bhr = bhh[u];
        float bhz = bhh[NH + u];
        float bhn = bhh[2 * NH + u];
#pragma unroll
        for (int i = 0; i < 4; ++i) {
            int m = m0 + lq * 4 + i;  // batch index
            long xbase = ((long)t * NB + m) * NG;
            float xr = bf2f(XP[xbase + u]);
            float xz = bf2f(XP[xbase + NH + u]);
            float xn = bf2f(XP[xbase + 2 * NH + u]);
            float hr = acc[0][f][i] + bhr;
            float hz = acc[1][f][i] + bhz;
            float hn = acc[2][f][i] + bhn;
            float r = 1.0f / (1.0f + __expf(-(xr + hr)));
            float z = 1.0f / (1.0f + __expf(-(xz + hz)));
            float a2 = xn + r * hn;
            // tanh(x) = 1 - 2/(exp(2x)+1); correct limits at +-inf
            float nval = 1.0f - 2.0f / (__expf(2.0f * a2) + 1.0f);
            float hold = hf_cur[(long)m * NH + u];
            float hnew = (1.0f - z) * nval + z * hold;
            hf_nxt[(long)m * NH + u] = hnew;
            hb_nxt[(long)m * NH + u] = f2bf(hnew);
            out[((long)m * NT + t) * NH + u] = hnew;
        }
    }
}

extern "C" void kernel_launch(void* const* d_in, const int* in_sizes, int n_in,
                              void* d_out, int out_size, void* d_ws, size_t ws_size,
                              hipStream_t stream) {
    const float* enc = (const float*)d_in[0];
    const float* Wih = (const float*)d_in[1];
    const float* Whh = (const float*)d_in[2];
    const float* bih = (const float*)d_in[3];
    const float* bhh = (const float*)d_in[4];
    float* out = (float*)d_out;

    // workspace carve (all 16B-aligned chunk sizes)
    char* p = (char*)d_ws;
    unsigned short* enc_t = (unsigned short*)p; p += (size_t)NT * NB * NH * 2;   // 64 MB
    unsigned short* xp    = (unsigned short*)p; p += (size_t)NT * NB * NG * 2;   // 192 MB
    unsigned short* wih_b = (unsigned short*)p; p += (size_t)NG * NH * 2;        // 6 MB
    unsigned short* whh_b = (unsigned short*)p; p += (size_t)NG * NH * 2;        // 6 MB
    unsigned short* hb0   = (unsigned short*)p; p += (size_t)NB * NH * 2;
    unsigned short* hb1   = (unsigned short*)p; p += (size_t)NB * NH * 2;
    float* hf0 = (float*)p; p += (size_t)NB * NH * 4;
    float* hf1 = (float*)p; p += (size_t)NB * NH * 4;
    size_t need = (size_t)(p - (char*)d_ws);

    if (ws_size < need) {
        // unambiguous failure signature: fill output with sentinel
        long n = (long)out_size;
        k_fill_sentinel<<<(int)((n + 255) / 256), 256, 0, stream>>>(out, n);
        return;
    }

    // Phase 0: conversions
    {
        int n = NG * NH;  // 3145728
        k_convert<<<(n + 255) / 256, 256, 0, stream>>>(Wih, wih_b, n);
        k_convert<<<(n + 255) / 256, 256, 0, stream>>>(Whh, whh_b, n);
        long ne = (long)NB * NT * NH;
        k_convert_enc<<<(int)((ne + 255) / 256), 256, 0, stream>>>(enc, enc_t);
        k_zero_h<<<(NB * NH + 255) / 256, 256, 0, stream>>>(hf0, hb0);
    }

    // Phase 1: x_proj GEMM
    {
        dim3 grid(NG / 128, (NT * NB) / 64);  // (24, 512)
        k_xproj<<<grid, 256, 0, stream>>>(enc_t, wih_b, bih, xp);
    }

    // Phase 2: sequential scan, double-buffered h
    unsigned short* hb[2] = {hb0, hb1};
    float* hf[2] = {hf0, hf1};
    for (int t = 0; t < NT; ++t) {
        int c = t & 1, nx = c ^ 1;
        k_step<<<32, 256, 0, stream>>>(whh_b, bhh, xp, hb[c], hf[c], hb[nx], hf[nx], out, t);
    }
}

// Round 2
// 11106.247 us; speedup vs baseline: 1.4133x; 1.4133x over previous
//
#include <hip/hip_runtime.h>
#include <hip/hip_bf16.h>

// GRU decoder: B=64, T=512, H=1024
// Phase 0: convert enc -> bf16 [T,B,H], W_ih/W_hh -> bf16; zero h0 + barrier flags
// Phase 1: x_proj GEMM (bf16 MFMA), output layout [T][64 ug][64 b][48]
// Phase 2: ONE persistent scan kernel, 256 blocks (4 batch-groups x 64 unit-groups),
//          Whh held in registers as MFMA fragments, per-group flag barriers.

typedef short bf16x8 __attribute__((ext_vector_type(8)));
typedef float f32x4 __attribute__((ext_vector_type(4)));

#define NB 64
#define NT 512
#define NH 1024
#define NG 3072  // 3*NH

static __device__ __forceinline__ float bf2f(unsigned short u) {
    unsigned int x = ((unsigned int)u) << 16;
    float f;
    __builtin_memcpy(&f, &x, sizeof(f));
    return f;
}
static __device__ __forceinline__ unsigned short f2bf(float f) {
    unsigned int x;
    __builtin_memcpy(&x, &f, sizeof(x));
    x += 0x7fffu + ((x >> 16) & 1u);  // round-to-nearest-even
    return (unsigned short)(x >> 16);
}

static __device__ __forceinline__ f32x4 mfma16(bf16x8 a, bf16x8 b, f32x4 c) {
    return __builtin_amdgcn_mfma_f32_16x16x32_bf16(a, b, c, 0, 0, 0);
}

__global__ void k_fill_sentinel(float* __restrict__ o, long n) {
    long i = (long)blockIdx.x * blockDim.x + threadIdx.x;
    if (i < n) o[i] = 12345.0f;
}

__global__ void k_convert(const float* __restrict__ in, unsigned short* __restrict__ o, int n) {
    int i = blockIdx.x * blockDim.x + threadIdx.x;
    if (i < n) o[i] = f2bf(in[i]);
}

// enc [B,T,H] f32 -> enc_t [T,B,H] bf16
__global__ void k_convert_enc(const float* __restrict__ enc, unsigned short* __restrict__ o) {
    long i = (long)blockIdx.x * blockDim.x + threadIdx.x;
    if (i >= (long)NB * NT * NH) return;
    int h = (int)(i % NH);
    long bt = i / NH;
    int t = (int)(bt % NT);
    int b = (int)(bt / NT);
    o[((long)t * NB + b) * NH + h] = f2bf(enc[i]);
}

// zero h0 (bf16) and the barrier flag region
__global__ void k_init_state(unsigned short* __restrict__ hb0, unsigned int* __restrict__ flags, int nflags) {
    int i = blockIdx.x * blockDim.x + threadIdx.x;
    if (i < NB * NH) hb0[i] = 0;
    if (i < nflags) flags[i] = 0;
}

// Phase 1 GEMM: pre[m, n] = sum_k X[m,k]*W[n,k] + bias[n], m = t*64+b over T*B, n over 3H.
// Block = 256 threads = 4 waves arranged 2(M)x2(N); block tile 64(M) x 128(N).
// Output layout: xp[((t*64 + ug)*64 + b)*48 + g*16 + ui]  (g = n>>10, u = n&1023, ug = u>>4, ui = u&15)
__global__ __launch_bounds__(256) void k_xproj(
    const unsigned short* __restrict__ X,   // [T*B, H] bf16
    const unsigned short* __restrict__ W,   // [3H, H] bf16
    const float* __restrict__ bias,         // [3H]
    unsigned short* __restrict__ xp)        // [T][64][64][48] bf16
{
    const int lane = threadIdx.x & 63;
    const int wv   = threadIdx.x >> 6;
    const int l16  = lane & 15;
    const int lq   = lane >> 4;
    const int n0   = blockIdx.x * 128 + (wv & 1) * 64;
    const int m0   = blockIdx.y * 64 + (wv >> 1) * 32;

    f32x4 acc[2][4];
#pragma unroll
    for (int a = 0; a < 2; ++a)
#pragma unroll
        for (int b = 0; b < 4; ++b) acc[a][b] = (f32x4){0.f, 0.f, 0.f, 0.f};

    for (int k0 = 0; k0 < NH; k0 += 32) {
        bf16x8 af[2];
#pragma unroll
        for (int mi = 0; mi < 2; ++mi)
            af[mi] = *(const bf16x8*)(X + (long)(m0 + mi * 16 + l16) * NH + k0 + lq * 8);
#pragma unroll
        for (int nj = 0; nj < 4; ++nj) {
            bf16x8 bfr = *(const bf16x8*)(W + (long)(n0 + nj * 16 + l16) * NH + k0 + lq * 8);
#pragma unroll
            for (int mi = 0; mi < 2; ++mi)
                acc[mi][nj] = mfma16(af[mi], bfr, acc[mi][nj]);
        }
    }

#pragma unroll
    for (int nj = 0; nj < 4; ++nj) {
        int n = n0 + nj * 16 + l16;
        float bv = bias[n];
        int g  = n >> 10;
        int u  = n & 1023;
        int ug = u >> 4;
        int ui = u & 15;
#pragma unroll
        for (int mi = 0; mi < 2; ++mi) {
#pragma unroll
            for (int i = 0; i < 4; ++i) {
                int m = m0 + mi * 16 + lq * 4 + i;
                int t = m >> 6;
                int b = m & 63;
                xp[(((long)t * 64 + ug) * 64 + b) * 48 + g * 16 + ui] = f2bf(acc[mi][nj][i] + bv);
            }
        }
    }
}

// ---- per-batch-group barrier (64 blocks per group) ----
// flags[mg*64 + ug] = last step this block arrived at; release[mg*32] = last released step.
static __device__ __forceinline__ void group_barrier(unsigned int* flags, unsigned int* release,
                                                     int mg, int ug, unsigned int target) {
    const int tid = threadIdx.x;
    __syncthreads();  // all block threads done with this step's reads/writes
    if (tid == 0) {
        __threadfence();  // make hb/out writes visible device-wide
        __hip_atomic_store(flags + mg * 64 + ug, target, __ATOMIC_RELEASE, __HIP_MEMORY_SCOPE_AGENT);
    }
    if (ug == 0) {
        if (tid < 64) {
            while (__hip_atomic_load(flags + mg * 64 + tid, __ATOMIC_RELAXED, __HIP_MEMORY_SCOPE_AGENT) != target)
                __builtin_amdgcn_s_sleep(2);
        }
        __syncthreads();
        if (tid == 0) {
            __threadfence();
            __hip_atomic_store(release + mg * 32, target, __ATOMIC_RELEASE, __HIP_MEMORY_SCOPE_AGENT);
        }
    } else {
        if (tid == 0) {
            while (__hip_atomic_load(release + mg * 32, __ATOMIC_RELAXED, __HIP_MEMORY_SCOPE_AGENT) != target)
                __builtin_amdgcn_s_sleep(2);
            __threadfence();  // invalidate stale cached h before next step's reads
        }
    }
    __syncthreads();
}

// Phase 2: persistent scan. Grid 256 = mg(4) x ug(64). Block 256 thr = 4 waves.
// Block owns batches m0..m0+15, units u0..u0+15 (x3 gates = 48 Whh rows held in regs).
// Wave wv handles K-chunk [wv*256, wv*256+256); partials reduced via LDS.
// Wave wv then owns batches {m0 + lq*4 + wv} for gate math + h writes (1 elem/lane).
__global__ __launch_bounds__(256, 2) void k_scan(
    const unsigned short* __restrict__ Whh,   // [3H, H] bf16
    const float* __restrict__ bhh,            // [3H]
    const unsigned short* __restrict__ xp,    // [T][64][64][48] bf16
    unsigned short* __restrict__ hb0,         // [B, H] bf16 (t even reads)
    unsigned short* __restrict__ hb1,         // [B, H] bf16 (t odd reads)
    float* __restrict__ out,                  // [B, T, H] f32
    unsigned int* __restrict__ flags,         // [256]
    unsigned int* __restrict__ release)       // [4*32]
{
    const int tid  = threadIdx.x;
    const int lane = tid & 63;
    const int wv   = tid >> 6;
    const int l16  = lane & 15;
    const int lq   = lane >> 4;
    const int bid  = blockIdx.x;
    const int mg   = bid >> 6;
    const int ug   = bid & 63;
    const int m0   = mg * 16;
    const int u0   = ug * 16;
    const int kc0  = wv * 256;

    // Hold this block's Whh slice as MFMA B-fragments for the whole scan.
    bf16x8 Bf[3][8];
#pragma unroll
    for (int g = 0; g < 3; ++g)
#pragma unroll
        for (int ks = 0; ks < 8; ++ks)
            Bf[g][ks] = *(const bf16x8*)(Whh + (long)(g * NH + u0 + l16) * NH + kc0 + ks * 32 + lq * 8);

    float bh[3];
#pragma unroll
    for (int g = 0; g < 3; ++g) bh[g] = bhh[g * NH + u0 + l16];

    const int b_own = m0 + lq * 4 + wv;  // batch this thread owns for gates/writes
    const int u_own = u0 + l16;
    float hf = 0.0f;                     // fp32 h for (b_own, u_own), lives in a register

    __shared__ f32x4 red[4][3][64];

    for (int t = 0; t < NT; ++t) {
        const unsigned short* hc = (t & 1) ? hb1 : hb0;
        unsigned short* hn       = (t & 1) ? hb0 : hb1;

        f32x4 acc[3];
#pragma unroll
        for (int g = 0; g < 3; ++g) acc[g] = (f32x4){0.f, 0.f, 0.f, 0.f};

#pragma unroll
        for (int ks = 0; ks < 8; ++ks) {
            bf16x8 af = *(const bf16x8*)(hc + (long)(m0 + l16) * NH + kc0 + ks * 32 + lq * 8);
#pragma unroll
            for (int g = 0; g < 3; ++g)
                acc[g] = mfma16(af, Bf[g][ks], acc[g]);
        }

#pragma unroll
        for (int g = 0; g < 3; ++g) red[wv][g][lane] = acc[g];
        __syncthreads();

        float pre[3];
#pragma unroll
        for (int g = 0; g < 3; ++g) {
            f32x4 s = red[0][g][lane] + red[1][g][lane] + red[2][g][lane] + red[3][g][lane];
            pre[g] = s[wv] + bh[g];
        }

        const unsigned short* xpp = xp + (((long)t * 64 + ug) * 64 + b_own) * 48;
        float xr = bf2f(xpp[l16]);
        float xz = bf2f(xpp[16 + l16]);
        float xn = bf2f(xpp[32 + l16]);

        float r = 1.0f / (1.0f + __expf(-(xr + pre[0])));
        float z = 1.0f / (1.0f + __expf(-(xz + pre[1])));
        float a2 = xn + r * pre[2];
        float nval = 1.0f - 2.0f / (__expf(2.0f * a2) + 1.0f);  // tanh
        float hnew = (1.0f - z) * nval + z * hf;
        hf = hnew;

        hn[(long)b_own * NH + u_own] = f2bf(hnew);
        out[((long)b_own * NT + t) * NH + u_own] = hnew;

        group_barrier(flags, release, mg, ug, (unsigned int)(t + 1));
    }
}

extern "C" void kernel_launch(void* const* d_in, const int* in_sizes, int n_in,
                              void* d_out, int out_size, void* d_ws, size_t ws_size,
                              hipStream_t stream) {
    const float* enc = (const float*)d_in[0];
    const float* Wih = (const float*)d_in[1];
    const float* Whh = (const float*)d_in[2];
    const float* bih = (const float*)d_in[3];
    const float* bhh = (const float*)d_in[4];
    float* out = (float*)d_out;

    // workspace carve
    char* p = (char*)d_ws;
    unsigned short* enc_t = (unsigned short*)p; p += (size_t)NT * NB * NH * 2;   // 64 MB
    unsigned short* xp    = (unsigned short*)p; p += (size_t)NT * NB * NG * 2;   // 192 MB
    unsigned short* wih_b = (unsigned short*)p; p += (size_t)NG * NH * 2;        // 6 MB
    unsigned short* whh_b = (unsigned short*)p; p += (size_t)NG * NH * 2;        // 6 MB
    unsigned short* hb0   = (unsigned short*)p; p += (size_t)NB * NH * 2;
    unsigned short* hb1   = (unsigned short*)p; p += (size_t)NB * NH * 2;
    unsigned int* flags   = (unsigned int*)p;  p += 256 * 4;
    unsigned int* release = (unsigned int*)p;  p += 4 * 32 * 4;
    size_t need = (size_t)(p - (char*)d_ws);

    if (ws_size < need) {
        long n = (long)out_size;
        k_fill_sentinel<<<(int)((n + 255) / 256), 256, 0, stream>>>(out, n);
        return;
    }

    // Phase 0: conversions + state init
    {
        int n = NG * NH;  // 3145728
        k_convert<<<(n + 255) / 256, 256, 0, stream>>>(Wih, wih_b, n);
        k_convert<<<(n + 255) / 256, 256, 0, stream>>>(Whh, whh_b, n);
        long ne = (long)NB * NT * NH;
        k_convert_enc<<<(int)((ne + 255) / 256), 256, 0, stream>>>(enc, enc_t);
        k_init_state<<<(NB * NH + 255) / 256, 256, 0, stream>>>(hb0, flags, 256 + 4 * 32);
    }

    // Phase 1: x_proj GEMM
    {
        dim3 grid(NG / 128, (NT * NB) / 64);  // (24, 512)
        k_xproj<<<grid, 256, 0, stream>>>(enc_t, wih_b, bih, xp);
    }

    // Phase 2: one persistent scan kernel
    k_scan<<<256, 256, 0, stream>>>(whh_b, bhh, xp, hb0, hb1, out, flags, release);
}

// Round 4
// 3609.150 us; speedup vs baseline: 4.3491x; 3.0772x over previous
//
#include <hip/hip_runtime.h>
#include <hip/hip_bf16.h>

// GRU decoder: B=64, T=512, H=1024
// Phase 0: convert enc -> bf16 [T,B,H], W_ih/W_hh -> bf16; zero h ring slot 3 + flags
// Phase 1: x_proj GEMM (bf16 MFMA), output layout [T][64 ug][64 b][48]
// Phase 2: ONE persistent scan kernel, 256 blocks (4 batch-groups x 64 unit-groups).
//          Whh pinned in registers; single-hop coherent flag barrier (sc0 sc1 ops,
//          no threadfence); 4-deep h ring buffer for loose WAR (>= t-2) bound.

typedef short bf16x8 __attribute__((ext_vector_type(8)));
typedef float f32x4 __attribute__((ext_vector_type(4)));

#define NB 64
#define NT 512
#define NH 1024
#define NG 3072  // 3*NH
#define HBUF (NB * NH)  // one h buffer, elements

static __device__ __forceinline__ float bf2f(unsigned short u) {
    unsigned int x = ((unsigned int)u) << 16;
    float f;
    __builtin_memcpy(&f, &x, sizeof(f));
    return f;
}
static __device__ __forceinline__ unsigned short f2bf(float f) {
    unsigned int x;
    __builtin_memcpy(&x, &f, sizeof(x));
    x += 0x7fffu + ((x >> 16) & 1u);  // round-to-nearest-even
    return (unsigned short)(x >> 16);
}

static __device__ __forceinline__ f32x4 mfma16(bf16x8 a, bf16x8 b, f32x4 c) {
    return __builtin_amdgcn_mfma_f32_16x16x32_bf16(a, b, c, 0, 0, 0);
}

__global__ void k_fill_sentinel(float* __restrict__ o, long n) {
    long i = (long)blockIdx.x * blockDim.x + threadIdx.x;
    if (i < n) o[i] = 12345.0f;
}

__global__ void k_convert(const float* __restrict__ in, unsigned short* __restrict__ o, int n) {
    int i = blockIdx.x * blockDim.x + threadIdx.x;
    if (i < n) o[i] = f2bf(in[i]);
}

// enc [B,T,H] f32 -> enc_t [T,B,H] bf16
__global__ void k_convert_enc(const float* __restrict__ enc, unsigned short* __restrict__ o) {
    long i = (long)blockIdx.x * blockDim.x + threadIdx.x;
    if (i >= (long)NB * NT * NH) return;
    int h = (int)(i % NH);
    long bt = i / NH;
    int t = (int)(bt % NT);
    int b = (int)(bt / NT);
    o[((long)t * NB + b) * NH + h] = f2bf(enc[i]);
}

// zero the t=-1 h buffer (ring slot 3) and the 256 barrier flags
__global__ void k_init_state(unsigned short* __restrict__ hb3, unsigned int* __restrict__ flags) {
    int i = blockIdx.x * blockDim.x + threadIdx.x;  // 65536 threads
    hb3[i] = 0;
    if (i < 256) flags[i] = 0;
}

// Phase 1 GEMM: pre[m, n] = sum_k X[m,k]*W[n,k] + bias[n], m = t*64+b over T*B, n over 3H.
// Block = 256 threads = 4 waves arranged 2(M)x2(N); block tile 64(M) x 128(N).
// Output layout: xp[((t*64 + ug)*64 + b)*48 + g*16 + ui]
__global__ __launch_bounds__(256) void k_xproj(
    const unsigned short* __restrict__ X,   // [T*B, H] bf16
    const unsigned short* __restrict__ W,   // [3H, H] bf16
    const float* __restrict__ bias,         // [3H]
    unsigned short* __restrict__ xp)        // [T][64][64][48] bf16
{
    const int lane = threadIdx.x & 63;
    const int wv   = threadIdx.x >> 6;
    const int l16  = lane & 15;
    const int lq   = lane >> 4;
    const int n0   = blockIdx.x * 128 + (wv & 1) * 64;
    const int m0   = blockIdx.y * 64 + (wv >> 1) * 32;

    f32x4 acc[2][4];
#pragma unroll
    for (int a = 0; a < 2; ++a)
#pragma unroll
        for (int b = 0; b < 4; ++b) acc[a][b] = (f32x4){0.f, 0.f, 0.f, 0.f};

    for (int k0 = 0; k0 < NH; k0 += 32) {
        bf16x8 af[2];
#pragma unroll
        for (int mi = 0; mi < 2; ++mi)
            af[mi] = *(const bf16x8*)(X + (long)(m0 + mi * 16 + l16) * NH + k0 + lq * 8);
#pragma unroll
        for (int nj = 0; nj < 4; ++nj) {
            bf16x8 bfr = *(const bf16x8*)(W + (long)(n0 + nj * 16 + l16) * NH + k0 + lq * 8);
#pragma unroll
            for (int mi = 0; mi < 2; ++mi)
                acc[mi][nj] = mfma16(af[mi], bfr, acc[mi][nj]);
        }
    }

#pragma unroll
    for (int nj = 0; nj < 4; ++nj) {
        int n = n0 + nj * 16 + l16;
        float bv = bias[n];
        int g  = n >> 10;
        int u  = n & 1023;
        int ug = u >> 4;
        int ui = u & 15;
#pragma unroll
        for (int mi = 0; mi < 2; ++mi) {
#pragma unroll
            for (int i = 0; i < 4; ++i) {
                int m = m0 + mi * 16 + lq * 4 + i;
                int t = m >> 6;
                int b = m & 63;
                xp[(((long)t * 64 + ug) * 64 + b) * 48 + g * 16 + ui] = f2bf(acc[mi][nj][i] + bv);
            }
        }
    }
}

// Phase 2: persistent scan. Grid 256 = mg(4) x ug(64). Block 256 thr = 4 waves.
// Block owns batches m0..m0+15, units u0..u0+15 (48 Whh rows pinned in regs).
// Wave wv handles K-chunk [wv*256, +256); partials reduced via LDS.
// h ring buffer of 4: step t reads slot (t+3)&3, writes slot t&3.
// Flags[mg*64+ug] = steps completed by that block. Per-step poll (single hop):
//   lane polls flags[mg*64+lane]; target = t for this wave's 16 producers,
//   max(t-2,0) for the rest (WAR bound for ring overwrite).
__global__ __launch_bounds__(256, 1) void k_scan(
    const unsigned short* __restrict__ Whh,   // [3H, H] bf16
    const float* __restrict__ bhh,            // [3H]
    const unsigned short* __restrict__ xp,    // [T][64][64][48] bf16
    unsigned short* __restrict__ hbase,       // 4 * [B, H] bf16 ring
    float* __restrict__ out,                  // [B, T, H] f32
    unsigned int* __restrict__ flags)         // [256]
{
    const int tid  = threadIdx.x;
    const int lane = tid & 63;
    const int wv   = tid >> 6;
    const int l16  = lane & 15;
    const int lq   = lane >> 4;
    const int bid  = blockIdx.x;
    const int mg   = bid >> 6;
    const int ug   = bid & 63;
    const int m0   = mg * 16;
    const int u0   = ug * 16;
    const int kc0  = wv * 256;

    // Whh slice as MFMA B-fragments, pinned in VGPRs for the whole scan.
    bf16x8 Bf[3][8];
#pragma unroll
    for (int g = 0; g < 3; ++g)
#pragma unroll
        for (int ks = 0; ks < 8; ++ks)
            Bf[g][ks] = *(const bf16x8*)(Whh + (long)(g * NH + u0 + l16) * NH + kc0 + ks * 32 + lq * 8);
#pragma unroll
    for (int g = 0; g < 3; ++g)
#pragma unroll
        for (int ks = 0; ks < 8; ++ks)
            asm volatile("" : "+v"(Bf[g][ks]));  // forbid rematerialization

    float bh[3];
#pragma unroll
    for (int g = 0; g < 3; ++g) bh[g] = bhh[g * NH + u0 + l16];

    const int b_own = m0 + lq * 4 + wv;   // batch this thread owns in epilogue
    const int u_own = u0 + l16;
    float hf = 0.0f;                      // fp32 h for (b_own,u_own), in-register

    const unsigned int* fmy = flags + mg * 64 + lane;   // this lane's polled flag
    unsigned int* fown = flags + mg * 64 + ug;          // this block's flag

    __shared__ f32x4 red[4][3][64];

    for (int t = 0; t < NT; ++t) {
        const unsigned short* hc = hbase + ((t + 3) & 3) * HBUF;
        unsigned short* hn       = hbase + (t & 3) * HBUF;

        // xp loads (normal cached; overlap with the poll below)
        const unsigned short* xpp = xp + (((long)t * 64 + ug) * 64 + b_own) * 48;
        float xr = bf2f(xpp[l16]);
        float xz = bf2f(xpp[16 + l16]);
        float xn = bf2f(xpp[32 + l16]);

        // single-hop poll, mixed targets
        if (t > 0) {
            unsigned int tgt = ((lane >> 4) == wv) ? (unsigned int)t
                                                   : (t >= 2 ? (unsigned int)(t - 2) : 0u);
            for (;;) {
                unsigned int f;
                asm volatile("global_load_dword %0, %1, off sc0 sc1\n\t"
                             "s_waitcnt vmcnt(0)"
                             : "=v"(f) : "v"(fmy) : "memory");
                if (__all(f >= tgt)) break;
                __builtin_amdgcn_s_sleep(2);
            }
        }

        // coherent h-chunk load: 8 x 16B per lane, one wait
        bf16x8 a0, a1, a2, a3, a4, a5, a6, a7;
        {
            const unsigned short* hp = hc + (long)(m0 + l16) * NH + kc0 + lq * 8;
            asm volatile(
                "global_load_dwordx4 %0, %8, off sc0 sc1\n\t"
                "global_load_dwordx4 %1, %8, off offset:64 sc0 sc1\n\t"
                "global_load_dwordx4 %2, %8, off offset:128 sc0 sc1\n\t"
                "global_load_dwordx4 %3, %8, off offset:192 sc0 sc1\n\t"
                "global_load_dwordx4 %4, %8, off offset:256 sc0 sc1\n\t"
                "global_load_dwordx4 %5, %8, off offset:320 sc0 sc1\n\t"
                "global_load_dwordx4 %6, %8, off offset:384 sc0 sc1\n\t"
                "global_load_dwordx4 %7, %8, off offset:448 sc0 sc1\n\t"
                "s_waitcnt vmcnt(0)"
                : "=&v"(a0), "=&v"(a1), "=&v"(a2), "=&v"(a3),
                  "=&v"(a4), "=&v"(a5), "=&v"(a6), "=&v"(a7)
                : "v"(hp) : "memory");
        }

        bf16x8 av[8] = {a0, a1, a2, a3, a4, a5, a6, a7};
        f32x4 acc[3];
#pragma unroll
        for (int g = 0; g < 3; ++g) acc[g] = (f32x4){0.f, 0.f, 0.f, 0.f};
#pragma unroll
        for (int ks = 0; ks < 8; ++ks)
#pragma unroll
            for (int g = 0; g < 3; ++g)
                acc[g] = mfma16(av[ks], Bf[g][ks], acc[g]);

#pragma unroll
        for (int g = 0; g < 3; ++g) red[wv][g][lane] = acc[g];
        __syncthreads();

        float pre[3];
#pragma unroll
        for (int g = 0; g < 3; ++g) {
            f32x4 s = red[0][g][lane] + red[1][g][lane] + red[2][g][lane] + red[3][g][lane];
            pre[g] = s[wv] + bh[g];
        }

        float r = 1.0f / (1.0f + __expf(-(xr + pre[0])));
        float z = 1.0f / (1.0f + __expf(-(xz + pre[1])));
        float narg = xn + r * pre[2];
        float nval = 1.0f - 2.0f / (__expf(2.0f * narg) + 1.0f);  // tanh
        float hnew = (1.0f - z) * nval + z * hf;
        hf = hnew;

        // coherent h store (2B) + normal out store
        {
            unsigned short* hpw = hn + (long)b_own * NH + u_own;
            unsigned int hv = (unsigned int)f2bf(hnew);
            asm volatile("global_store_short %0, %1, off sc0 sc1"
                         :: "v"(hpw), "v"(hv) : "memory");
        }
        out[((long)b_own * NT + t) * NH + u_own] = hnew;

        asm volatile("s_waitcnt vmcnt(0)" ::: "memory");  // h visible at L3
        __syncthreads();                                   // all waves done
        if (tid == 0) {
            unsigned int fv = (unsigned int)(t + 1);
            asm volatile("global_store_dword %0, %1, off sc0 sc1"
                         :: "v"(fown), "v"(fv) : "memory");
        }
    }
}

extern "C" void kernel_launch(void* const* d_in, const int* in_sizes, int n_in,
                              void* d_out, int out_size, void* d_ws, size_t ws_size,
                              hipStream_t stream) {
    const float* enc = (const float*)d_in[0];
    const float* Wih = (const float*)d_in[1];
    const float* Whh = (const float*)d_in[2];
    const float* bih = (const float*)d_in[3];
    const float* bhh = (const float*)d_in[4];
    float* out = (float*)d_out;

    // workspace carve
    char* p = (char*)d_ws;
    unsigned short* enc_t = (unsigned short*)p; p += (size_t)NT * NB * NH * 2;   // 64 MB
    unsigned short* xp    = (unsigned short*)p; p += (size_t)NT * NB * NG * 2;   // 192 MB
    unsigned short* wih_b = (unsigned short*)p; p += (size_t)NG * NH * 2;        // 6 MB
    unsigned short* whh_b = (unsigned short*)p; p += (size_t)NG * NH * 2;        // 6 MB
    unsigned short* hbase = (unsigned short*)p; p += (size_t)4 * HBUF * 2;       // 512 KB
    unsigned int* flags   = (unsigned int*)p;  p += 256 * 4;
    size_t need = (size_t)(p - (char*)d_ws);

    if (ws_size < need) {
        long n = (long)out_size;
        k_fill_sentinel<<<(int)((n + 255) / 256), 256, 0, stream>>>(out, n);
        return;
    }

    // Phase 0: conversions + state init
    {
        int n = NG * NH;  // 3145728
        k_convert<<<(n + 255) / 256, 256, 0, stream>>>(Wih, wih_b, n);
        k_convert<<<(n + 255) / 256, 256, 0, stream>>>(Whh, whh_b, n);
        long ne = (long)NB * NT * NH;
        k_convert_enc<<<(int)((ne + 255) / 256), 256, 0, stream>>>(enc, enc_t);
        k_init_state<<<HBUF / 256, 256, 0, stream>>>(hbase + 3 * HBUF, flags);
    }

    // Phase 1: x_proj GEMM
    {
        dim3 grid(NG / 128, (NT * NB) / 64);  // (24, 512)
        k_xproj<<<grid, 256, 0, stream>>>(enc_t, wih_b, bih, xp);
    }

    // Phase 2: one persistent scan kernel
    k_scan<<<256, 256, 0, stream>>>(whh_b, bhh, xp, hbase, out, flags);
}

// Round 5
// 3566.066 us; speedup vs baseline: 4.4017x; 1.0121x over previous
//
#include <hip/hip_runtime.h>
#include <hip/hip_bf16.h>

// GRU decoder: B=64, T=512, H=1024
// Phase 0: convert enc -> bf16 [T,B,H], W_ih/W_hh -> bf16
// Phase 1: x_proj GEMM (bf16 MFMA), output layout [T][64 ug][64 b][48]
// Phase 1.5: zero tagged-h ring (aliases dead enc_t region)
// Phase 2: ONE persistent scan kernel, 256 blocks (4 batch-groups x 64 unit-groups).
//          Whh pinned in registers. Cross-block h exchange via TAGGED WORDS
//          {tag=t+1 | bf16 h} stored sc0 sc1: consumers poll data directly
//          (single L3 round trip), no flags, no producer store-ack.
//          Ring depth 4; skew<=1 proven by all-to-all consumption.

typedef short bf16x8 __attribute__((ext_vector_type(8)));
typedef float f32x4 __attribute__((ext_vector_type(4)));
typedef unsigned int u32x4 __attribute__((ext_vector_type(4)));

#define NB 64
#define NT 512
#define NH 1024
#define NG 3072           // 3*NH
#define HWORDS (NB * NH)  // one tagged-h ring slot, words

static __device__ __forceinline__ float bf2f(unsigned short u) {
    unsigned int x = ((unsigned int)u) << 16;
    float f;
    __builtin_memcpy(&f, &x, sizeof(f));
    return f;
}
static __device__ __forceinline__ unsigned short f2bf(float f) {
    unsigned int x;
    __builtin_memcpy(&x, &f, sizeof(x));
    x += 0x7fffu + ((x >> 16) & 1u);  // round-to-nearest-even
    return (unsigned short)(x >> 16);
}

static __device__ __forceinline__ f32x4 mfma16(bf16x8 a, bf16x8 b, f32x4 c) {
    return __builtin_amdgcn_mfma_f32_16x16x32_bf16(a, b, c, 0, 0, 0);
}

static __device__ __forceinline__ unsigned umin2(unsigned a, unsigned b) { return a < b ? a : b; }
static __device__ __forceinline__ unsigned umin4(u32x4 a) {
    return umin2(umin2(a[0], a[1]), umin2(a[2], a[3]));
}
// build bf16x8 fragment from 8 tagged words (low halves)
static __device__ __forceinline__ bf16x8 pack8(u32x4 a, u32x4 b) {
    union { unsigned u[4]; bf16x8 v; } r;
    r.u[0] = (a[0] & 0xffffu) | (a[1] << 16);
    r.u[1] = (a[2] & 0xffffu) | (a[3] << 16);
    r.u[2] = (b[0] & 0xffffu) | (b[1] << 16);
    r.u[3] = (b[2] & 0xffffu) | (b[3] << 16);
    return r.v;
}

__global__ void k_fill_sentinel(float* __restrict__ o, long n) {
    long i = (long)blockIdx.x * blockDim.x + threadIdx.x;
    if (i < n) o[i] = 12345.0f;
}

__global__ void k_convert(const float* __restrict__ in, unsigned short* __restrict__ o, int n) {
    int i = blockIdx.x * blockDim.x + threadIdx.x;
    if (i < n) o[i] = f2bf(in[i]);
}

// enc [B,T,H] f32 -> enc_t [T,B,H] bf16
__global__ void k_convert_enc(const float* __restrict__ enc, unsigned short* __restrict__ o) {
    long i = (long)blockIdx.x * blockDim.x + threadIdx.x;
    if (i >= (long)NB * NT * NH) return;
    int h = (int)(i % NH);
    long bt = i / NH;
    int t = (int)(bt % NT);
    int b = (int)(bt / NT);
    o[((long)t * NB + b) * NH + h] = f2bf(enc[i]);
}

// zero all 4 tagged-h ring slots (poison 0xAA would spoof "fresh" tags)
__global__ void k_init_ht(unsigned int* __restrict__ ht) {
    int i = blockIdx.x * blockDim.x + threadIdx.x;  // 4*65536 threads
    ht[i] = 0u;  // tag 0, h = 0
}

// Phase 1 GEMM: pre[m, n] = sum_k X[m,k]*W[n,k] + bias[n], m = t*64+b over T*B, n over 3H.
// Block = 256 threads = 4 waves arranged 2(M)x2(N); block tile 64(M) x 128(N).
// Output layout: xp[((t*64 + ug)*64 + b)*48 + g*16 + ui]
__global__ __launch_bounds__(256) void k_xproj(
    const unsigned short* __restrict__ X,   // [T*B, H] bf16
    const unsigned short* __restrict__ W,   // [3H, H] bf16
    const float* __restrict__ bias,         // [3H]
    unsigned short* __restrict__ xp)        // [T][64][64][48] bf16
{
    const int lane = threadIdx.x & 63;
    const int wv   = threadIdx.x >> 6;
    const int l16  = lane & 15;
    const int lq   = lane >> 4;
    const int n0   = blockIdx.x * 128 + (wv & 1) * 64;
    const int m0   = blockIdx.y * 64 + (wv >> 1) * 32;

    f32x4 acc[2][4];
#pragma unroll
    for (int a = 0; a < 2; ++a)
#pragma unroll
        for (int b = 0; b < 4; ++b) acc[a][b] = (f32x4){0.f, 0.f, 0.f, 0.f};

    for (int k0 = 0; k0 < NH; k0 += 32) {
        bf16x8 af[2];
#pragma unroll
        for (int mi = 0; mi < 2; ++mi)
            af[mi] = *(const bf16x8*)(X + (long)(m0 + mi * 16 + l16) * NH + k0 + lq * 8);
#pragma unroll
        for (int nj = 0; nj < 4; ++nj) {
            bf16x8 bfr = *(const bf16x8*)(W + (long)(n0 + nj * 16 + l16) * NH + k0 + lq * 8);
#pragma unroll
            for (int mi = 0; mi < 2; ++mi)
                acc[mi][nj] = mfma16(af[mi], bfr, acc[mi][nj]);
        }
    }

#pragma unroll
    for (int nj = 0; nj < 4; ++nj) {
        int n = n0 + nj * 16 + l16;
        float bv = bias[n];
        int g  = n >> 10;
        int u  = n & 1023;
        int ug = u >> 4;
        int ui = u & 15;
#pragma unroll
        for (int mi = 0; mi < 2; ++mi) {
#pragma unroll
            for (int i = 0; i < 4; ++i) {
                int m = m0 + mi * 16 + lq * 4 + i;
                int t = m >> 6;
                int b = m & 63;
                xp[(((long)t * 64 + ug) * 64 + b) * 48 + g * 16 + ui] = f2bf(acc[mi][nj][i] + bv);
            }
        }
    }
}

// Phase 2: persistent scan. Grid 256 = mg(4) x ug(64). Block 256 thr = 4 waves.
// Block owns batches m0..m0+15, units u0..u0+15 (48 Whh rows pinned in regs).
// Wave wv handles K-chunk [wv*256, +256); partials reduced via double-buffered LDS.
// Tagged-h ring: step t reads slot (t+3)&3 expecting tag==t (min-check),
// writes slot t&3 with tag t+1. No flags. Poll vmcnt(0) also drains old stores,
// guaranteeing same-address ordering across ring passes.
__global__ __launch_bounds__(256, 1) void k_scan(
    const unsigned short* __restrict__ Whh,   // [3H, H] bf16
    const float* __restrict__ bhh,            // [3H]
    const unsigned short* __restrict__ xp,    // [T][64][64][48] bf16
    unsigned int* __restrict__ ht,            // 4 * [B, H] tagged words
    float* __restrict__ out)                  // [B, T, H] f32
{
    const int tid  = threadIdx.x;
    const int lane = tid & 63;
    const int wv   = tid >> 6;
    const int l16  = lane & 15;
    const int lq   = lane >> 4;
    const int bid  = blockIdx.x;
    const int mg   = bid >> 6;
    const int ug   = bid & 63;
    const int m0   = mg * 16;
    const int u0   = ug * 16;
    const int kc0  = wv * 256;

    // Whh slice as MFMA B-fragments, pinned for the whole scan.
    bf16x8 Bf[3][8];
#pragma unroll
    for (int g = 0; g < 3; ++g)
#pragma unroll
        for (int ks = 0; ks < 8; ++ks)
            Bf[g][ks] = *(const bf16x8*)(Whh + (long)(g * NH + u0 + l16) * NH + kc0 + ks * 32 + lq * 8);
#pragma unroll
    for (int g = 0; g < 3; ++g)
#pragma unroll
        for (int ks = 0; ks < 8; ++ks)
            asm volatile("" : "+v"(Bf[g][ks]));  // forbid rematerialization

    float bh[3];
#pragma unroll
    for (int g = 0; g < 3; ++g) bh[g] = bhh[g * NH + u0 + l16];

    const int b_own = m0 + lq * 4 + wv;   // batch this thread owns in epilogue
    const int u_own = u0 + l16;
    float hf = 0.0f;                      // fp32 h for (b_own,u_own), in-register

    __shared__ f32x4 red[2][4][3][64];

    for (int t = 0; t < NT; ++t) {
        const int slot_r = (t + 3) & 3;
        const int slot_w = t & 3;
        const int pb     = t & 1;

        // xp loads (normal cached; overlap with the poll)
        const unsigned short* xpp = xp + (((long)t * 64 + ug) * 64 + b_own) * 48;
        float xr = bf2f(xpp[l16]);
        float xz = bf2f(xpp[16 + l16]);
        float xn = bf2f(xpp[32 + l16]);

        // ---- poll-on-tagged-data: one L3 round trip per iteration ----
        const unsigned int* hp = ht + ((unsigned)(slot_r * NB + m0 + l16) * NH + kc0 + lq * 8);
        const unsigned int thr = (unsigned int)t << 16;
        u32x4 w0, w1, w2, w3, w4, w5, w6, w7, w8, w9, w10, w11, w12, w13, w14, w15;
        for (;;) {
            asm volatile(
                "global_load_dwordx4 %0, %16, off sc0 sc1\n\t"
                "global_load_dwordx4 %1, %16, off offset:16 sc0 sc1\n\t"
                "global_load_dwordx4 %2, %16, off offset:128 sc0 sc1\n\t"
                "global_load_dwordx4 %3, %16, off offset:144 sc0 sc1\n\t"
                "global_load_dwordx4 %4, %16, off offset:256 sc0 sc1\n\t"
                "global_load_dwordx4 %5, %16, off offset:272 sc0 sc1\n\t"
                "global_load_dwordx4 %6, %16, off offset:384 sc0 sc1\n\t"
                "global_load_dwordx4 %7, %16, off offset:400 sc0 sc1\n\t"
                "global_load_dwordx4 %8, %16, off offset:512 sc0 sc1\n\t"
                "global_load_dwordx4 %9, %16, off offset:528 sc0 sc1\n\t"
                "global_load_dwordx4 %10, %16, off offset:640 sc0 sc1\n\t"
                "global_load_dwordx4 %11, %16, off offset:656 sc0 sc1\n\t"
                "global_load_dwordx4 %12, %16, off offset:768 sc0 sc1\n\t"
                "global_load_dwordx4 %13, %16, off offset:784 sc0 sc1\n\t"
                "global_load_dwordx4 %14, %16, off offset:896 sc0 sc1\n\t"
                "global_load_dwordx4 %15, %16, off offset:912 sc0 sc1\n\t"
                "s_waitcnt vmcnt(0)"
                : "=&v"(w0), "=&v"(w1), "=&v"(w2), "=&v"(w3),
                  "=&v"(w4), "=&v"(w5), "=&v"(w6), "=&v"(w7),
                  "=&v"(w8), "=&v"(w9), "=&v"(w10), "=&v"(w11),
                  "=&v"(w12), "=&v"(w13), "=&v"(w14), "=&v"(w15)
                : "v"(hp) : "memory");
            unsigned m = umin2(umin2(umin2(umin4(w0), umin4(w1)), umin2(umin4(w2), umin4(w3))),
                               umin2(umin2(umin4(w4), umin4(w5)), umin2(umin4(w6), umin4(w7))));
            m = umin2(m, umin2(umin2(umin2(umin4(w8), umin4(w9)), umin2(umin4(w10), umin4(w11))),
                               umin2(umin2(umin4(w12), umin4(w13)), umin2(umin4(w14), umin4(w15)))));
            if (__all(m >= thr)) break;
            __builtin_amdgcn_s_sleep(1);
        }

        bf16x8 av[8];
        av[0] = pack8(w0, w1);   av[1] = pack8(w2, w3);
        av[2] = pack8(w4, w5);   av[3] = pack8(w6, w7);
        av[4] = pack8(w8, w9);   av[5] = pack8(w10, w11);
        av[6] = pack8(w12, w13); av[7] = pack8(w14, w15);

        f32x4 acc[3];
#pragma unroll
        for (int g = 0; g < 3; ++g) acc[g] = (f32x4){0.f, 0.f, 0.f, 0.f};
#pragma unroll
        for (int ks = 0; ks < 8; ++ks)
#pragma unroll
            for (int g = 0; g < 3; ++g)
                acc[g] = mfma16(av[ks], Bf[g][ks], acc[g]);

#pragma unroll
        for (int g = 0; g < 3; ++g) red[pb][wv][g][lane] = acc[g];
        __syncthreads();

        float pre[3];
#pragma unroll
        for (int g = 0; g < 3; ++g) {
            f32x4 s = red[pb][0][g][lane] + red[pb][1][g][lane] + red[pb][2][g][lane] + red[pb][3][g][lane];
            pre[g] = s[wv] + bh[g];
        }

        float r = 1.0f / (1.0f + __expf(-(xr + pre[0])));
        float z = 1.0f / (1.0f + __expf(-(xz + pre[1])));
        float narg = xn + r * pre[2];
        float nval = 1.0f - 2.0f / (__expf(2.0f * narg) + 1.0f);  // tanh
        float hnew = (1.0f - z) * nval + z * hf;
        hf = hnew;

        // tagged h store (fire-and-forget, sc0 sc1) + normal out store
        {
            unsigned int* hw = ht + (unsigned)(slot_w * NB + b_own) * NH + u_own;
            unsigned int tv = ((unsigned int)(t + 1) << 16) | (unsigned int)f2bf(hnew);
            asm volatile("global_store_dword %0, %1, off sc0 sc1"
                         :: "v"(hw), "v"(tv) : "memory");
        }
        out[((long)b_own * NT + t) * NH + u_own] = hnew;
        // no wait: next step's poll vmcnt(0) drains these stores.
    }
}

extern "C" void kernel_launch(void* const* d_in, const int* in_sizes, int n_in,
                              void* d_out, int out_size, void* d_ws, size_t ws_size,
                              hipStream_t stream) {
    const float* enc = (const float*)d_in[0];
    const float* Wih = (const float*)d_in[1];
    const float* Whh = (const float*)d_in[2];
    const float* bih = (const float*)d_in[3];
    const float* bhh = (const float*)d_in[4];
    float* out = (float*)d_out;

    // workspace carve
    char* p = (char*)d_ws;
    unsigned short* enc_t = (unsigned short*)p; p += (size_t)NT * NB * NH * 2;   // 64 MB
    unsigned short* xp    = (unsigned short*)p; p += (size_t)NT * NB * NG * 2;   // 192 MB
    unsigned short* wih_b = (unsigned short*)p; p += (size_t)NG * NH * 2;        // 6 MB
    unsigned short* whh_b = (unsigned short*)p; p += (size_t)NG * NH * 2;        // 6 MB
    size_t need = (size_t)(p - (char*)d_ws);
    // tagged-h ring (1 MB) aliases the dead enc_t region (enc_t consumed by k_xproj)
    unsigned int* ht = (unsigned int*)enc_t;

    if (ws_size < need) {
        long n = (long)out_size;
        k_fill_sentinel<<<(int)((n + 255) / 256), 256, 0, stream>>>(out, n);
        return;
    }

    // Phase 0: conversions
    {
        int n = NG * NH;  // 3145728
        k_convert<<<(n + 255) / 256, 256, 0, stream>>>(Wih, wih_b, n);
        k_convert<<<(n + 255) / 256, 256, 0, stream>>>(Whh, whh_b, n);
        long ne = (long)NB * NT * NH;
        k_convert_enc<<<(int)((ne + 255) / 256), 256, 0, stream>>>(enc, enc_t);
    }

    // Phase 1: x_proj GEMM (reads enc_t)
    {
        dim3 grid(NG / 128, (NT * NB) / 64);  // (24, 512)
        k_xproj<<<grid, 256, 0, stream>>>(enc_t, wih_b, bih, xp);
    }

    // Phase 1.5: zero the tagged-h ring (after enc_t is dead)
    k_init_ht<<<4 * HWORDS / 256, 256, 0, stream>>>(ht);

    // Phase 2: one persistent scan kernel
    k_scan<<<256, 256, 0, stream>>>(whh_b, bhh, xp, ht, out);
}

// Round 6
// 3252.468 us; speedup vs baseline: 4.8261x; 1.0964x over previous
//
#include <hip/hip_runtime.h>
#include <hip/hip_bf16.h>

// GRU decoder: B=64, T=512, H=1024
// Phase 0: convert enc -> bf16 [T,B,H], W_ih/W_hh -> bf16
// Phase 1: x_proj GEMM (bf16 MFMA), output layout [T][32 ugb][64 b][96]
// Phase 1.5: zero tagged-h ring (aliases dead enc_t region)
// Phase 2: ONE persistent scan kernel, 128 blocks x 512 thr (8 waves).
//          4 batch-groups x 32 unit-blocks (16 batches x 32 units each).
//          Whh pinned in registers (96 VGPR/lane). Cross-block h exchange via
//          TAGGED WORDS {tag=t+1 | bf16 h} sc0 sc1; each wave's K-chunk (128)
//          has only 4 producer blocks -> waves unblock independently.

typedef short bf16x8 __attribute__((ext_vector_type(8)));
typedef float f32x4 __attribute__((ext_vector_type(4)));
typedef unsigned int u32x4 __attribute__((ext_vector_type(4)));

#define NB 64
#define NT 512
#define NH 1024
#define NG 3072           // 3*NH
#define HWORDS (NB * NH)  // one tagged-h ring slot, words

static __device__ __forceinline__ float bf2f(unsigned short u) {
    unsigned int x = ((unsigned int)u) << 16;
    float f;
    __builtin_memcpy(&f, &x, sizeof(f));
    return f;
}
static __device__ __forceinline__ unsigned short f2bf(float f) {
    unsigned int x;
    __builtin_memcpy(&x, &f, sizeof(x));
    x += 0x7fffu + ((x >> 16) & 1u);  // round-to-nearest-even
    return (unsigned short)(x >> 16);
}

static __device__ __forceinline__ f32x4 mfma16(bf16x8 a, bf16x8 b, f32x4 c) {
    return __builtin_amdgcn_mfma_f32_16x16x32_bf16(a, b, c, 0, 0, 0);
}

static __device__ __forceinline__ unsigned umin2(unsigned a, unsigned b) { return a < b ? a : b; }
static __device__ __forceinline__ unsigned umin4(u32x4 a) {
    return umin2(umin2(a[0], a[1]), umin2(a[2], a[3]));
}
// build bf16x8 fragment from 8 tagged words (low halves)
static __device__ __forceinline__ bf16x8 pack8(u32x4 a, u32x4 b) {
    union { unsigned u[4]; bf16x8 v; } r;
    r.u[0] = (a[0] & 0xffffu) | (a[1] << 16);
    r.u[1] = (a[2] & 0xffffu) | (a[3] << 16);
    r.u[2] = (b[0] & 0xffffu) | (b[1] << 16);
    r.u[3] = (b[2] & 0xffffu) | (b[3] << 16);
    return r.v;
}

__global__ void k_fill_sentinel(float* __restrict__ o, long n) {
    long i = (long)blockIdx.x * blockDim.x + threadIdx.x;
    if (i < n) o[i] = 12345.0f;
}

__global__ void k_convert(const float* __restrict__ in, unsigned short* __restrict__ o, int n) {
    int i = blockIdx.x * blockDim.x + threadIdx.x;
    if (i < n) o[i] = f2bf(in[i]);
}

// enc [B,T,H] f32 -> enc_t [T,B,H] bf16
__global__ void k_convert_enc(const float* __restrict__ enc, unsigned short* __restrict__ o) {
    long i = (long)blockIdx.x * blockDim.x + threadIdx.x;
    if (i >= (long)NB * NT * NH) return;
    int h = (int)(i % NH);
    long bt = i / NH;
    int t = (int)(bt % NT);
    int b = (int)(bt / NT);
    o[((long)t * NB + b) * NH + h] = f2bf(enc[i]);
}

// zero all 4 tagged-h ring slots (poison 0xAA would spoof "fresh" tags)
__global__ void k_init_ht(unsigned int* __restrict__ ht) {
    int i = blockIdx.x * blockDim.x + threadIdx.x;  // 4*65536 threads
    ht[i] = 0u;  // tag 0, h = 0
}

// Phase 1 GEMM: pre[m, n] = sum_k X[m,k]*W[n,k] + bias[n], m = t*64+b over T*B, n over 3H.
// Block = 256 threads = 4 waves arranged 2(M)x2(N); block tile 64(M) x 128(N).
// Output layout: xp[((t*32 + ugb)*64 + b)*96 + g*32 + ui]  (ugb = u>>5, ui = u&31)
__global__ __launch_bounds__(256) void k_xproj(
    const unsigned short* __restrict__ X,   // [T*B, H] bf16
    const unsigned short* __restrict__ W,   // [3H, H] bf16
    const float* __restrict__ bias,         // [3H]
    unsigned short* __restrict__ xp)        // [T][32][64][96] bf16
{
    const int lane = threadIdx.x & 63;
    const int wv   = threadIdx.x >> 6;
    const int l16  = lane & 15;
    const int lq   = lane >> 4;
    const int n0   = blockIdx.x * 128 + (wv & 1) * 64;
    const int m0   = blockIdx.y * 64 + (wv >> 1) * 32;

    f32x4 acc[2][4];
#pragma unroll
    for (int a = 0; a < 2; ++a)
#pragma unroll
        for (int b = 0; b < 4; ++b) acc[a][b] = (f32x4){0.f, 0.f, 0.f, 0.f};

    for (int k0 = 0; k0 < NH; k0 += 32) {
        bf16x8 af[2];
#pragma unroll
        for (int mi = 0; mi < 2; ++mi)
            af[mi] = *(const bf16x8*)(X + (long)(m0 + mi * 16 + l16) * NH + k0 + lq * 8);
#pragma unroll
        for (int nj = 0; nj < 4; ++nj) {
            bf16x8 bfr = *(const bf16x8*)(W + (long)(n0 + nj * 16 + l16) * NH + k0 + lq * 8);
#pragma unroll
            for (int mi = 0; mi < 2; ++mi)
                acc[mi][nj] = mfma16(af[mi], bfr, acc[mi][nj]);
        }
    }

#pragma unroll
    for (int nj = 0; nj < 4; ++nj) {
        int n = n0 + nj * 16 + l16;
        float bv = bias[n];
        int g   = n >> 10;
        int u   = n & 1023;
        int ugb = u >> 5;
        int ui  = u & 31;
#pragma unroll
        for (int mi = 0; mi < 2; ++mi) {
#pragma unroll
            for (int i = 0; i < 4; ++i) {
                int m = m0 + mi * 16 + lq * 4 + i;
                int t = m >> 6;
                int b = m & 63;
                xp[(((long)t * 32 + ugb) * 64 + b) * 96 + g * 32 + ui] = f2bf(acc[mi][nj][i] + bv);
            }
        }
    }
}

// Phase 2: persistent scan. Grid 128 = mg(4) x ug(32). Block 512 thr = 8 waves.
// Block owns batches m0..m0+15, units u0..u0+31 (96 Whh rows pinned in regs).
// Wave wv handles K-chunk [wv*128, +128) -> its h comes from exactly 4 producer
// blocks. Partials reduced via LDS (8 waves), epilogue 1 output/thread.
// Tagged-h ring depth 4: step t reads slot (t+3)&3 expecting tag>=t (min-check),
// writes slot t&3 with tag t+1. Poll vmcnt(0) drains own prior stores ->
// same-address ordering across ring passes.
__global__ __launch_bounds__(512, 1) void k_scan(
    const unsigned short* __restrict__ Whh,   // [3H, H] bf16
    const float* __restrict__ bhh,            // [3H]
    const unsigned short* __restrict__ xp,    // [T][32][64][96] bf16
    unsigned int* __restrict__ ht,            // 4 * [B, H] tagged words
    float* __restrict__ out)                  // [B, T, H] f32
{
    const int tid  = threadIdx.x;
    const int lane = tid & 63;
    const int wv   = tid >> 6;        // 0..7
    const int l16  = lane & 15;
    const int lq   = lane >> 4;
    const int bid  = blockIdx.x;
    const int mg   = bid >> 5;        // 0..3
    const int ug   = bid & 31;        // 0..31
    const int m0   = mg * 16;
    const int u0   = ug * 32;
    const int kc0  = wv * 128;

    // Whh slice as MFMA B-fragments, pinned for the whole scan.
    // Bf[g][f][ks]: gate g, unit-frag f (u0+f*16..+16), kstep ks (K=kc0+ks*32)
    bf16x8 Bf[3][2][4];
#pragma unroll
    for (int g = 0; g < 3; ++g)
#pragma unroll
        for (int f = 0; f < 2; ++f)
#pragma unroll
            for (int ks = 0; ks < 4; ++ks)
                Bf[g][f][ks] = *(const bf16x8*)(Whh + (long)(g * NH + u0 + f * 16 + l16) * NH + kc0 + ks * 32 + lq * 8);
#pragma unroll
    for (int g = 0; g < 3; ++g)
#pragma unroll
        for (int f = 0; f < 2; ++f)
#pragma unroll
            for (int ks = 0; ks < 4; ++ks)
                asm volatile("" : "+v"(Bf[g][f][ks]));  // forbid rematerialization

    // epilogue ownership: 1 output (b_own, u_own) per thread
    const int u_loc = tid & 31;
    const int b_loc = tid >> 5;       // 0..15
    const int b_own = m0 + b_loc;
    const int u_own = u0 + u_loc;
    float bh[3];
#pragma unroll
    for (int g = 0; g < 3; ++g) bh[g] = bhh[g * NH + u_own];
    float hf = 0.0f;                  // fp32 h for (b_own,u_own), in-register

    // C-frag element holding (b_loc, u_loc&15): lane=(b_loc>>2)*16+(u_loc&15), elem=b_loc&3
    const int lane_t = (b_loc >> 2) * 16 + (u_loc & 15);
    const int i_t    = b_loc & 3;
    const int shalf  = (u_loc >> 4) * 3;   // frag-slot base: 0 or 3

    __shared__ f32x4 red[8][6][64];   // 48 KB

    for (int t = 0; t < NT; ++t) {
        const int slot_r = (t + 3) & 3;
        const int slot_w = t & 3;

        // xp loads for epilogue (plain cached; overlap with the poll)
        const unsigned short* xpp = xp + (((long)t * 32 + ug) * 64 + b_own) * 96;
        float xr = bf2f(xpp[u_loc]);
        float xz = bf2f(xpp[32 + u_loc]);
        float xn = bf2f(xpp[64 + u_loc]);

        // ---- poll-on-tagged-data: 8 x dwordx4 = 128B/lane/attempt ----
        const unsigned int* hp = ht + ((unsigned)(slot_r * NB + m0 + l16) * NH + kc0 + lq * 8);
        const unsigned int thr = (unsigned int)t << 16;
        u32x4 w0, w1, w2, w3, w4, w5, w6, w7;
        for (;;) {
            asm volatile(
                "global_load_dwordx4 %0, %8, off sc0 sc1\n\t"
                "global_load_dwordx4 %1, %8, off offset:16 sc0 sc1\n\t"
                "global_load_dwordx4 %2, %8, off offset:128 sc0 sc1\n\t"
                "global_load_dwordx4 %3, %8, off offset:144 sc0 sc1\n\t"
                "global_load_dwordx4 %4, %8, off offset:256 sc0 sc1\n\t"
                "global_load_dwordx4 %5, %8, off offset:272 sc0 sc1\n\t"
                "global_load_dwordx4 %6, %8, off offset:384 sc0 sc1\n\t"
                "global_load_dwordx4 %7, %8, off offset:400 sc0 sc1\n\t"
                "s_waitcnt vmcnt(0)"
                : "=&v"(w0), "=&v"(w1), "=&v"(w2), "=&v"(w3),
                  "=&v"(w4), "=&v"(w5), "=&v"(w6), "=&v"(w7)
                : "v"(hp) : "memory");
            unsigned m = umin2(umin2(umin4(w0), umin4(w1)), umin2(umin4(w2), umin4(w3)));
            m = umin2(m, umin2(umin2(umin4(w4), umin4(w5)), umin2(umin4(w6), umin4(w7))));
            if (__all(m >= thr)) break;
            __builtin_amdgcn_s_sleep(1);
        }

        bf16x8 av[4];
        av[0] = pack8(w0, w1); av[1] = pack8(w2, w3);
        av[2] = pack8(w4, w5); av[3] = pack8(w6, w7);

        f32x4 acc[2][3];
#pragma unroll
        for (int f = 0; f < 2; ++f)
#pragma unroll
            for (int g = 0; g < 3; ++g) acc[f][g] = (f32x4){0.f, 0.f, 0.f, 0.f};
#pragma unroll
        for (int ks = 0; ks < 4; ++ks)
#pragma unroll
            for (int f = 0; f < 2; ++f)
#pragma unroll
                for (int g = 0; g < 3; ++g)
                    acc[f][g] = mfma16(av[ks], Bf[g][f][ks], acc[f][g]);

#pragma unroll
        for (int f = 0; f < 2; ++f)
#pragma unroll
            for (int g = 0; g < 3; ++g) red[wv][f * 3 + g][lane] = acc[f][g];
        __syncthreads();

        float pre[3];
#pragma unroll
        for (int g = 0; g < 3; ++g) {
            float s = 0.0f;
#pragma unroll
            for (int w = 0; w < 8; ++w) s += red[w][shalf + g][lane_t][i_t];
            pre[g] = s + bh[g];
        }

        float r = 1.0f / (1.0f + __expf(-(xr + pre[0])));
        float z = 1.0f / (1.0f + __expf(-(xz + pre[1])));
        float narg = xn + r * pre[2];
        float nval = 1.0f - 2.0f / (__expf(2.0f * narg) + 1.0f);  // tanh
        float hnew = (1.0f - z) * nval + z * hf;
        hf = hnew;

        // tagged h store (fire-and-forget, sc0 sc1) + normal out store
        {
            unsigned int* hw = ht + (unsigned)(slot_w * NB + b_own) * NH + u_own;
            unsigned int tv = ((unsigned int)(t + 1) << 16) | (unsigned int)f2bf(hnew);
            asm volatile("global_store_dword %0, %1, off sc0 sc1"
                         :: "v"(hw), "v"(tv) : "memory");
        }
        out[((long)b_own * NT + t) * NH + u_own] = hnew;

        __syncthreads();  // protect red[] from next-iteration overwrite
        // no vmcnt wait: next step's poll vmcnt(0) drains the tagged store.
    }
}

extern "C" void kernel_launch(void* const* d_in, const int* in_sizes, int n_in,
                              void* d_out, int out_size, void* d_ws, size_t ws_size,
                              hipStream_t stream) {
    const float* enc = (const float*)d_in[0];
    const float* Wih = (const float*)d_in[1];
    const float* Whh = (const float*)d_in[2];
    const float* bih = (const float*)d_in[3];
    const float* bhh = (const float*)d_in[4];
    float* out = (float*)d_out;

    // workspace carve
    char* p = (char*)d_ws;
    unsigned short* enc_t = (unsigned short*)p; p += (size_t)NT * NB * NH * 2;   // 64 MB
    unsigned short* xp    = (unsigned short*)p; p += (size_t)NT * NB * NG * 2;   // 192 MB
    unsigned short* wih_b = (unsigned short*)p; p += (size_t)NG * NH * 2;        // 6 MB
    unsigned short* whh_b = (unsigned short*)p; p += (size_t)NG * NH * 2;        // 6 MB
    size_t need = (size_t)(p - (char*)d_ws);
    // tagged-h ring (1 MB) aliases the dead enc_t region (enc_t consumed by k_xproj)
    unsigned int* ht = (unsigned int*)enc_t;

    if (ws_size < need) {
        long n = (long)out_size;
        k_fill_sentinel<<<(int)((n + 255) / 256), 256, 0, stream>>>(out, n);
        return;
    }

    // Phase 0: conversions
    {
        int n = NG * NH;  // 3145728
        k_convert<<<(n + 255) / 256, 256, 0, stream>>>(Wih, wih_b, n);
        k_convert<<<(n + 255) / 256, 256, 0, stream>>>(Whh, whh_b, n);
        long ne = (long)NB * NT * NH;
        k_convert_enc<<<(int)((ne + 255) / 256), 256, 0, stream>>>(enc, enc_t);
    }

    // Phase 1: x_proj GEMM (reads enc_t)
    {
        dim3 grid(NG / 128, (NT * NB) / 64);  // (24, 512)
        k_xproj<<<grid, 256, 0, stream>>>(enc_t, wih_b, bih, xp);
    }

    // Phase 1.5: zero the tagged-h ring (after enc_t is dead)
    k_init_ht<<<4 * HWORDS / 256, 256, 0, stream>>>(ht);

    // Phase 2: one persistent scan kernel
    k_scan<<<128, 512, 0, stream>>>(whh_b, bhh, xp, ht, out);
}

// Round 9
// 2523.494 us; speedup vs baseline: 6.2202x; 1.2889x over previous
//
#include <hip/hip_runtime.h>
#include <hip/hip_bf16.h>

// GRU decoder: B=64, T=512, H=1024
// Phase 0: convert enc -> bf16 [T,B,H], W_ih/W_hh -> bf16
// Phase 1: x_proj GEMM, m97-style: 128x128 tile, BK=32, global_load_lds staging.
//          Output layout [T][32 ugb][64 b][96]
// Phase 1.5: zero tagged-h ring (aliases dead enc_t region)
// Phase 2: persistent scan (PROVEN round-6 kernel, verbatim): 128 blocks x 512 thr,
//          4 batch-groups x 32 unit-blocks, Whh pinned in regs, tagged-word
//          h exchange via sc0 sc1 (L3-coherent), ring depth 4.

typedef short bf16x8 __attribute__((ext_vector_type(8)));
typedef float f32x4 __attribute__((ext_vector_type(4)));
typedef unsigned int u32x4 __attribute__((ext_vector_type(4)));

#define NB 64
#define NT 512
#define NH 1024
#define NG 3072           // 3*NH
#define HWORDS (NB * NH)  // one tagged-h ring slot, words

static __device__ __forceinline__ float bf2f(unsigned short u) {
    unsigned int x = ((unsigned int)u) << 16;
    float f;
    __builtin_memcpy(&f, &x, sizeof(f));
    return f;
}
static __device__ __forceinline__ unsigned short f2bf(float f) {
    unsigned int x;
    __builtin_memcpy(&x, &f, sizeof(x));
    x += 0x7fffu + ((x >> 16) & 1u);  // round-to-nearest-even
    return (unsigned short)(x >> 16);
}

static __device__ __forceinline__ f32x4 mfma16(bf16x8 a, bf16x8 b, f32x4 c) {
    return __builtin_amdgcn_mfma_f32_16x16x32_bf16(a, b, c, 0, 0, 0);
}

static __device__ __forceinline__ unsigned umin2(unsigned a, unsigned b) { return a < b ? a : b; }
static __device__ __forceinline__ unsigned umin4(u32x4 a) {
    return umin2(umin2(a[0], a[1]), umin2(a[2], a[3]));
}
// build bf16x8 fragment from 8 tagged words (low halves)
static __device__ __forceinline__ bf16x8 pack8(u32x4 a, u32x4 b) {
    union { unsigned u[4]; bf16x8 v; } r;
    r.u[0] = (a[0] & 0xffffu) | (a[1] << 16);
    r.u[1] = (a[2] & 0xffffu) | (a[3] << 16);
    r.u[2] = (b[0] & 0xffffu) | (b[1] << 16);
    r.u[3] = (b[2] & 0xffffu) | (b[3] << 16);
    return r.v;
}

// async global->LDS, 16B per lane; LDS dest = wave-uniform base + lane*16
#define GLD16(gp, lp) __builtin_amdgcn_global_load_lds( \
    (const __attribute__((address_space(1))) void*)(gp), \
    (__attribute__((address_space(3))) void*)(lp), 16, 0, 0)

__global__ void k_fill_sentinel(float* __restrict__ o, long n) {
    long i = (long)blockIdx.x * blockDim.x + threadIdx.x;
    if (i < n) o[i] = 12345.0f;
}

__global__ void k_convert(const float* __restrict__ in, unsigned short* __restrict__ o, int n) {
    int i = blockIdx.x * blockDim.x + threadIdx.x;
    if (i < n) o[i] = f2bf(in[i]);
}

// enc [B,T,H] f32 -> enc_t [T,B,H] bf16
__global__ void k_convert_enc(const float* __restrict__ enc, unsigned short* __restrict__ o) {
    long i = (long)blockIdx.x * blockDim.x + threadIdx.x;
    if (i >= (long)NB * NT * NH) return;
    int h = (int)(i % NH);
    long bt = i / NH;
    int t = (int)(bt % NT);
    int b = (int)(bt / NT);
    o[((long)t * NB + b) * NH + h] = f2bf(enc[i]);
}

// zero all 4 tagged-h ring slots (poison 0xAA would spoof "fresh" tags)
__global__ void k_init_ht(unsigned int* __restrict__ ht) {
    int i = blockIdx.x * blockDim.x + threadIdx.x;  // 4*65536 threads
    ht[i] = 0u;  // tag 0, h = 0
}

// Phase 1 GEMM, m97 structure: C[m,n] = sum_k X[m,k]*W[n,k] + bias[n]
// M = T*B = 32768, N = 3072, K = 1024. Grid (N/128, M/128) = (24, 256), 256 thr.
// LDS: As/Bs [128][32] bf16 (8 KB each), staged via global_load_lds width 16.
// Wave wv -> (wr,wc) = (wv>>1, wv&1): 64x64 wave tile = 4x4 frags of 16x16.
// Output layout: xp[((t*32 + ugb)*64 + b)*96 + g*32 + ui]
__global__ __launch_bounds__(256) void k_xproj(
    const unsigned short* __restrict__ X,   // [M, K] bf16
    const unsigned short* __restrict__ W,   // [N, K] bf16
    const float* __restrict__ bias,         // [N]
    unsigned short* __restrict__ xp)        // [T][32][64][96] bf16
{
    __shared__ unsigned short As[128 * 32];
    __shared__ unsigned short Bs[128 * 32];

    const int tid  = threadIdx.x;
    const int lane = tid & 63;
    const int wv   = tid >> 6;
    const int l16  = lane & 15;
    const int lq   = lane >> 4;
    const int wr   = wv >> 1;
    const int wc   = wv & 1;
    const int n0   = blockIdx.x * 128;
    const int m0   = blockIdx.y * 128;

    f32x4 acc[4][4];
#pragma unroll
    for (int mi = 0; mi < 4; ++mi)
#pragma unroll
        for (int nj = 0; nj < 4; ++nj) acc[mi][nj] = (f32x4){0.f, 0.f, 0.f, 0.f};

    // staging coords for this thread (chunk c = p*256 + tid; 16B per chunk)
    const int r0 = tid >> 2;           // pass 0 row
    const int c0e = (tid & 3) * 8;     // pass 0 col (elems)
    const int r1 = (256 + tid) >> 2;   // pass 1 row
    // pass 1 col elems same as pass 0 (c&3 unchanged by +256)

    for (int k0 = 0; k0 < NH; k0 += 32) {
        GLD16(X + (size_t)(m0 + r0) * NH + k0 + c0e, &As[tid * 8]);
        GLD16(X + (size_t)(m0 + r1) * NH + k0 + c0e, &As[(256 + tid) * 8]);
        GLD16(W + (size_t)(n0 + r0) * NH + k0 + c0e, &Bs[tid * 8]);
        GLD16(W + (size_t)(n0 + r1) * NH + k0 + c0e, &Bs[(256 + tid) * 8]);
        __syncthreads();  // drains vmcnt (global_load_lds) per compiler barrier semantics

        bf16x8 a[4], b[4];
#pragma unroll
        for (int mi = 0; mi < 4; ++mi)
            a[mi] = *(const bf16x8*)&As[(wr * 64 + mi * 16 + l16) * 32 + lq * 8];
#pragma unroll
        for (int nj = 0; nj < 4; ++nj)
            b[nj] = *(const bf16x8*)&Bs[(wc * 64 + nj * 16 + l16) * 32 + lq * 8];
#pragma unroll
        for (int mi = 0; mi < 4; ++mi)
#pragma unroll
            for (int nj = 0; nj < 4; ++nj)
                acc[mi][nj] = mfma16(a[mi], b[nj], acc[mi][nj]);
        __syncthreads();  // before next stage overwrites As/Bs
    }

#pragma unroll
    for (int nj = 0; nj < 4; ++nj) {
        int n = n0 + wc * 64 + nj * 16 + l16;
        float bv = bias[n];
        int g   = n >> 10;
        int u   = n & 1023;
        int ugb = u >> 5;
        int ui  = u & 31;
#pragma unroll
        for (int mi = 0; mi < 4; ++mi) {
#pragma unroll
            for (int i = 0; i < 4; ++i) {
                int m = m0 + wr * 64 + mi * 16 + lq * 4 + i;
                int t = m >> 6;
                int b = m & 63;
                xp[(((long)t * 32 + ugb) * 64 + b) * 96 + g * 32 + ui] = f2bf(acc[mi][nj][i] + bv);
            }
        }
    }
}

// Phase 2: persistent scan (round-6 proven kernel, verbatim).
// Grid 128 = mg(4) x ug(32). Block 512 thr = 8 waves.
// Block owns batches m0..m0+15, units u0..u0+31 (96 Whh rows pinned in regs).
// Wave wv handles K-chunk [wv*128, +128) -> its h comes from exactly 4 producer
// blocks. Partials reduced via LDS (8 waves), epilogue 1 output/thread.
// Tagged-h ring depth 4: step t reads slot (t+3)&3 expecting tag>=t (min-check),
// writes slot t&3 with tag t+1. Poll vmcnt(0) drains own prior stores ->
// same-address ordering across ring passes.
__global__ __launch_bounds__(512, 1) void k_scan(
    const unsigned short* __restrict__ Whh,   // [3H, H] bf16
    const float* __restrict__ bhh,            // [3H]
    const unsigned short* __restrict__ xp,    // [T][32][64][96] bf16
    unsigned int* __restrict__ ht,            // 4 * [B, H] tagged words
    float* __restrict__ out)                  // [B, T, H] f32
{
    const int tid  = threadIdx.x;
    const int lane = tid & 63;
    const int wv   = tid >> 6;        // 0..7
    const int l16  = lane & 15;
    const int lq   = lane >> 4;
    const int bid  = blockIdx.x;
    const int mg   = bid >> 5;        // 0..3
    const int ug   = bid & 31;        // 0..31
    const int m0   = mg * 16;
    const int u0   = ug * 32;
    const int kc0  = wv * 128;

    // Whh slice as MFMA B-fragments, pinned for the whole scan.
    bf16x8 Bf[3][2][4];
#pragma unroll
    for (int g = 0; g < 3; ++g)
#pragma unroll
        for (int f = 0; f < 2; ++f)
#pragma unroll
            for (int ks = 0; ks < 4; ++ks)
                Bf[g][f][ks] = *(const bf16x8*)(Whh + (long)(g * NH + u0 + f * 16 + l16) * NH + kc0 + ks * 32 + lq * 8);
#pragma unroll
    for (int g = 0; g < 3; ++g)
#pragma unroll
        for (int f = 0; f < 2; ++f)
#pragma unroll
            for (int ks = 0; ks < 4; ++ks)
                asm volatile("" : "+v"(Bf[g][f][ks]));  // forbid rematerialization

    // epilogue ownership: 1 output (b_own, u_own) per thread
    const int u_loc = tid & 31;
    const int b_loc = tid >> 5;       // 0..15
    const int b_own = m0 + b_loc;
    const int u_own = u0 + u_loc;
    float bh[3];
#pragma unroll
    for (int g = 0; g < 3; ++g) bh[g] = bhh[g * NH + u_own];
    float hf = 0.0f;                  // fp32 h for (b_own,u_own), in-register

    // C-frag element holding (b_loc, u_loc&15): lane=(b_loc>>2)*16+(u_loc&15), elem=b_loc&3
    const int lane_t = (b_loc >> 2) * 16 + (u_loc & 15);
    const int i_t    = b_loc & 3;
    const int shalf  = (u_loc >> 4) * 3;   // frag-slot base: 0 or 3

    __shared__ f32x4 red[8][6][64];   // 48 KB

    for (int t = 0; t < NT; ++t) {
        const int slot_r = (t + 3) & 3;
        const int slot_w = t & 3;

        // xp loads for epilogue (plain cached; overlap with the poll)
        const unsigned short* xpp = xp + (((long)t * 32 + ug) * 64 + b_own) * 96;
        float xr = bf2f(xpp[u_loc]);
        float xz = bf2f(xpp[32 + u_loc]);
        float xn = bf2f(xpp[64 + u_loc]);

        // ---- poll-on-tagged-data: 8 x dwordx4 = 128B/lane/attempt ----
        const unsigned int* hp = ht + ((unsigned)(slot_r * NB + m0 + l16) * NH + kc0 + lq * 8);
        const unsigned int thr = (unsigned int)t << 16;
        u32x4 w0, w1, w2, w3, w4, w5, w6, w7;
        for (;;) {
            asm volatile(
                "global_load_dwordx4 %0, %8, off sc0 sc1\n\t"
                "global_load_dwordx4 %1, %8, off offset:16 sc0 sc1\n\t"
                "global_load_dwordx4 %2, %8, off offset:128 sc0 sc1\n\t"
                "global_load_dwordx4 %3, %8, off offset:144 sc0 sc1\n\t"
                "global_load_dwordx4 %4, %8, off offset:256 sc0 sc1\n\t"
                "global_load_dwordx4 %5, %8, off offset:272 sc0 sc1\n\t"
                "global_load_dwordx4 %6, %8, off offset:384 sc0 sc1\n\t"
                "global_load_dwordx4 %7, %8, off offset:400 sc0 sc1\n\t"
                "s_waitcnt vmcnt(0)"
                : "=&v"(w0), "=&v"(w1), "=&v"(w2), "=&v"(w3),
                  "=&v"(w4), "=&v"(w5), "=&v"(w6), "=&v"(w7)
                : "v"(hp) : "memory");
            unsigned m = umin2(umin2(umin4(w0), umin4(w1)), umin2(umin4(w2), umin4(w3)));
            m = umin2(m, umin2(umin2(umin4(w4), umin4(w5)), umin2(umin4(w6), umin4(w7))));
            if (__all(m >= thr)) break;
            __builtin_amdgcn_s_sleep(1);
        }

        bf16x8 av[4];
        av[0] = pack8(w0, w1); av[1] = pack8(w2, w3);
        av[2] = pack8(w4, w5); av[3] = pack8(w6, w7);

        f32x4 acc[2][3];
#pragma unroll
        for (int f = 0; f < 2; ++f)
#pragma unroll
            for (int g = 0; g < 3; ++g) acc[f][g] = (f32x4){0.f, 0.f, 0.f, 0.f};
#pragma unroll
        for (int ks = 0; ks < 4; ++ks)
#pragma unroll
            for (int f = 0; f < 2; ++f)
#pragma unroll
                for (int g = 0; g < 3; ++g)
                    acc[f][g] = mfma16(av[ks], Bf[g][f][ks], acc[f][g]);

#pragma unroll
        for (int f = 0; f < 2; ++f)
#pragma unroll
            for (int g = 0; g < 3; ++g) red[wv][f * 3 + g][lane] = acc[f][g];
        __syncthreads();

        float pre[3];
#pragma unroll
        for (int g = 0; g < 3; ++g) {
            float s = 0.0f;
#pragma unroll
            for (int w = 0; w < 8; ++w) s += red[w][shalf + g][lane_t][i_t];
            pre[g] = s + bh[g];
        }

        float r = 1.0f / (1.0f + __expf(-(xr + pre[0])));
        float z = 1.0f / (1.0f + __expf(-(xz + pre[1])));
        float narg = xn + r * pre[2];
        float nval = 1.0f - 2.0f / (__expf(2.0f * narg) + 1.0f);  // tanh
        float hnew = (1.0f - z) * nval + z * hf;
        hf = hnew;

        // tagged h store (fire-and-forget, sc0 sc1) + normal out store
        {
            unsigned int* hw = ht + (unsigned)(slot_w * NB + b_own) * NH + u_own;
            unsigned int tv = ((unsigned int)(t + 1) << 16) | (unsigned int)f2bf(hnew);
            asm volatile("global_store_dword %0, %1, off sc0 sc1"
                         :: "v"(hw), "v"(tv) : "memory");
        }
        out[((long)b_own * NT + t) * NH + u_own] = hnew;

        __syncthreads();  // protect red[] from next-iteration overwrite
        // no vmcnt wait: next step's poll vmcnt(0) drains the tagged store.
    }
}

extern "C" void kernel_launch(void* const* d_in, const int* in_sizes, int n_in,
                              void* d_out, int out_size, void* d_ws, size_t ws_size,
                              hipStream_t stream) {
    const float* enc = (const float*)d_in[0];
    const float* Wih = (const float*)d_in[1];
    const float* Whh = (const float*)d_in[2];
    const float* bih = (const float*)d_in[3];
    const float* bhh = (const float*)d_in[4];
    float* out = (float*)d_out;

    // workspace carve
    char* p = (char*)d_ws;
    unsigned short* enc_t = (unsigned short*)p; p += (size_t)NT * NB * NH * 2;   // 64 MB
    unsigned short* xp    = (unsigned short*)p; p += (size_t)NT * NB * NG * 2;   // 192 MB
    unsigned short* wih_b = (unsigned short*)p; p += (size_t)NG * NH * 2;        // 6 MB
    unsigned short* whh_b = (unsigned short*)p; p += (size_t)NG * NH * 2;        // 6 MB
    size_t need = (size_t)(p - (char*)d_ws);
    // tagged-h ring (1 MB) aliases the dead enc_t region (enc_t consumed by k_xproj)
    unsigned int* ht = (unsigned int*)enc_t;

    if (ws_size < need) {
        long n = (long)out_size;
        k_fill_sentinel<<<(int)((n + 255) / 256), 256, 0, stream>>>(out, n);
        return;
    }

    // Phase 0: conversions
    {
        int n = NG * NH;  // 3145728
        k_convert<<<(n + 255) / 256, 256, 0, stream>>>(Wih, wih_b, n);
        k_convert<<<(n + 255) / 256, 256, 0, stream>>>(Whh, whh_b, n);
        long ne = (long)NB * NT * NH;
        k_convert_enc<<<(int)((ne + 255) / 256), 256, 0, stream>>>(enc, enc_t);
    }

    // Phase 1: x_proj GEMM (reads enc_t)
    {
        dim3 grid(NG / 128, (NT * NB) / 128);  // (24, 256)
        k_xproj<<<grid, 256, 0, stream>>>(enc_t, wih_b, bih, xp);
    }

    // Phase 1.5: zero the tagged-h ring (after enc_t is dead)
    k_init_ht<<<4 * HWORDS / 256, 256, 0, stream>>>(ht);

    // Phase 2: one persistent scan kernel
    k_scan<<<128, 512, 0, stream>>>(whh_b, bhh, xp, ht, out);
}

// Round 10
// 2306.695 us; speedup vs baseline: 6.8048x; 1.0940x over previous
//
#include <hip/hip_runtime.h>
#include <hip/hip_bf16.h>

// GRU decoder: B=64, T=512, H=1024
// Phase 0: convert enc -> bf16 [T,B,H], W_ih/W_hh -> bf16
// Phase 1: x_proj GEMM, m97-style (128x128 tile, BK=32, global_load_lds)
// Phase 1.5: zero h ring + flags (aliases dead enc_t region)
// Phase 2: persistent scan, 128 blocks x 512 thr, 4 batch-groups x 32 unit-blocks.
//   LOW-TRAFFIC protocol: producer drains h stores (vmcnt0 + barrier) then one
//   flag store per block; consumer: ONE wave polls the 32 group flags (1 dword
//   per lane, no payload), barrier-releases the block, data loaded exactly once.

typedef short bf16x8 __attribute__((ext_vector_type(8)));
typedef float f32x4 __attribute__((ext_vector_type(4)));

#define NB 64
#define NT 512
#define NH 1024
#define NG 3072           // 3*NH

static __device__ __forceinline__ float bf2f(unsigned short u) {
    unsigned int x = ((unsigned int)u) << 16;
    float f;
    __builtin_memcpy(&f, &x, sizeof(f));
    return f;
}
static __device__ __forceinline__ unsigned short f2bf(float f) {
    unsigned int x;
    __builtin_memcpy(&x, &f, sizeof(x));
    x += 0x7fffu + ((x >> 16) & 1u);  // round-to-nearest-even
    return (unsigned short)(x >> 16);
}

static __device__ __forceinline__ f32x4 mfma16(bf16x8 a, bf16x8 b, f32x4 c) {
    return __builtin_amdgcn_mfma_f32_16x16x32_bf16(a, b, c, 0, 0, 0);
}

// async global->LDS, 16B per lane; LDS dest = wave-uniform base + lane*16
#define GLD16(gp, lp) __builtin_amdgcn_global_load_lds( \
    (const __attribute__((address_space(1))) void*)(gp), \
    (__attribute__((address_space(3))) void*)(lp), 16, 0, 0)

__global__ void k_fill_sentinel(float* __restrict__ o, long n) {
    long i = (long)blockIdx.x * blockDim.x + threadIdx.x;
    if (i < n) o[i] = 12345.0f;
}

__global__ void k_convert(const float* __restrict__ in, unsigned short* __restrict__ o, int n) {
    int i = blockIdx.x * blockDim.x + threadIdx.x;
    if (i < n) o[i] = f2bf(in[i]);
}

// enc [B,T,H] f32 -> enc_t [T,B,H] bf16
__global__ void k_convert_enc(const float* __restrict__ enc, unsigned short* __restrict__ o) {
    long i = (long)blockIdx.x * blockDim.x + threadIdx.x;
    if (i >= (long)NB * NT * NH) return;
    int h = (int)(i % NH);
    long bt = i / NH;
    int t = (int)(bt % NT);
    int b = (int)(bt / NT);
    o[((long)t * NB + b) * NH + h] = f2bf(enc[i]);
}

// zero h ring (4*64*1024 bf16 = 131072 u32) + flags (128 u32)
#define SYNC_WORDS (4 * NB * NH / 2 + 128)
__global__ void k_init_sync(unsigned int* __restrict__ base) {
    int i = blockIdx.x * blockDim.x + threadIdx.x;
    if (i < SYNC_WORDS) base[i] = 0u;
}

// Phase 1 GEMM, m97 structure (unchanged from round 9).
__global__ __launch_bounds__(256) void k_xproj(
    const unsigned short* __restrict__ X,   // [M, K] bf16
    const unsigned short* __restrict__ W,   // [N, K] bf16
    const float* __restrict__ bias,         // [N]
    unsigned short* __restrict__ xp)        // [T][32][64][96] bf16
{
    __shared__ unsigned short As[128 * 32];
    __shared__ unsigned short Bs[128 * 32];

    const int tid  = threadIdx.x;
    const int lane = tid & 63;
    const int wv   = tid >> 6;
    const int l16  = lane & 15;
    const int lq   = lane >> 4;
    const int wr   = wv >> 1;
    const int wc   = wv & 1;
    const int n0   = blockIdx.x * 128;
    const int m0   = blockIdx.y * 128;

    f32x4 acc[4][4];
#pragma unroll
    for (int mi = 0; mi < 4; ++mi)
#pragma unroll
        for (int nj = 0; nj < 4; ++nj) acc[mi][nj] = (f32x4){0.f, 0.f, 0.f, 0.f};

    const int r0 = tid >> 2;
    const int c0e = (tid & 3) * 8;
    const int r1 = (256 + tid) >> 2;

    for (int k0 = 0; k0 < NH; k0 += 32) {
        GLD16(X + (size_t)(m0 + r0) * NH + k0 + c0e, &As[tid * 8]);
        GLD16(X + (size_t)(m0 + r1) * NH + k0 + c0e, &As[(256 + tid) * 8]);
        GLD16(W + (size_t)(n0 + r0) * NH + k0 + c0e, &Bs[tid * 8]);
        GLD16(W + (size_t)(n0 + r1) * NH + k0 + c0e, &Bs[(256 + tid) * 8]);
        __syncthreads();

        bf16x8 a[4], b[4];
#pragma unroll
        for (int mi = 0; mi < 4; ++mi)
            a[mi] = *(const bf16x8*)&As[(wr * 64 + mi * 16 + l16) * 32 + lq * 8];
#pragma unroll
        for (int nj = 0; nj < 4; ++nj)
            b[nj] = *(const bf16x8*)&Bs[(wc * 64 + nj * 16 + l16) * 32 + lq * 8];
#pragma unroll
        for (int mi = 0; mi < 4; ++mi)
#pragma unroll
            for (int nj = 0; nj < 4; ++nj)
                acc[mi][nj] = mfma16(a[mi], b[nj], acc[mi][nj]);
        __syncthreads();
    }

#pragma unroll
    for (int nj = 0; nj < 4; ++nj) {
        int n = n0 + wc * 64 + nj * 16 + l16;
        float bv = bias[n];
        int g   = n >> 10;
        int u   = n & 1023;
        int ugb = u >> 5;
        int ui  = u & 31;
#pragma unroll
        for (int mi = 0; mi < 4; ++mi) {
#pragma unroll
            for (int i = 0; i < 4; ++i) {
                int m = m0 + wr * 64 + mi * 16 + lq * 4 + i;
                int t = m >> 6;
                int b = m & 63;
                xp[(((long)t * 32 + ugb) * 64 + b) * 96 + g * 32 + ui] = f2bf(acc[mi][nj][i] + bv);
            }
        }
    }
}

// Phase 2: persistent scan, low-traffic flag protocol.
// Grid 128 = mg(4) x ug(32). Block 512 thr = 8 waves.
// Block owns batches m0..m0+15, units u0..u0+31 (96 Whh rows pinned in regs).
// Wave wv handles K-chunk [wv*128, +128). h ring [4][64][1024] bf16:
// step t reads slot (t+3)&3 (= h[t-1]) after wave0 confirms all 32 group flags
// >= t; writes slot t&3, drains (vmcnt0+barrier), tid0 stores flag = t+1.
__global__ __launch_bounds__(512, 1) void k_scan(
    const unsigned short* __restrict__ Whh,   // [3H, H] bf16
    const float* __restrict__ bhh,            // [3H]
    const unsigned short* __restrict__ xp,    // [T][32][64][96] bf16
    unsigned short* __restrict__ hring,       // [4][64][1024] bf16
    unsigned* __restrict__ flags,             // [128] = [mg*32+ug]
    float* __restrict__ out)                  // [B, T, H] f32
{
    const int tid  = threadIdx.x;
    const int lane = tid & 63;
    const int wv   = tid >> 6;        // 0..7
    const int l16  = lane & 15;
    const int lq   = lane >> 4;
    const int bid  = blockIdx.x;
    const int mg   = bid >> 5;        // 0..3
    const int ug   = bid & 31;        // 0..31
    const int m0   = mg * 16;
    const int u0   = ug * 32;
    const int kc0  = wv * 128;

    // Whh slice as MFMA B-fragments, pinned for the whole scan.
    bf16x8 Bf[3][2][4];
#pragma unroll
    for (int g = 0; g < 3; ++g)
#pragma unroll
        for (int f = 0; f < 2; ++f)
#pragma unroll
            for (int ks = 0; ks < 4; ++ks)
                Bf[g][f][ks] = *(const bf16x8*)(Whh + (long)(g * NH + u0 + f * 16 + l16) * NH + kc0 + ks * 32 + lq * 8);
#pragma unroll
    for (int g = 0; g < 3; ++g)
#pragma unroll
        for (int f = 0; f < 2; ++f)
#pragma unroll
            for (int ks = 0; ks < 4; ++ks)
                asm volatile("" : "+v"(Bf[g][f][ks]));  // forbid rematerialization

    // epilogue ownership: 1 output (b_own, u_own) per thread
    const int u_loc = tid & 31;
    const int b_loc = tid >> 5;       // 0..15
    const int b_own = m0 + b_loc;
    const int u_own = u0 + u_loc;
    float bh[3];
#pragma unroll
    for (int g = 0; g < 3; ++g) bh[g] = bhh[g * NH + u_own];
    float hf = 0.0f;                  // fp32 h for (b_own,u_own), in-register

    // C-frag element holding (b_loc, u_loc&15)
    const int lane_t = (b_loc >> 2) * 16 + (u_loc & 15);
    const int i_t    = b_loc & 3;
    const int shalf  = (u_loc >> 4) * 3;   // frag-slot base: 0 or 3

    __shared__ f32x4 red[8][6][64];   // 48 KB

    for (int t = 0; t < NT; ++t) {
        const int slot_r = (t + 3) & 3;
        const int slot_w = t & 3;

        // xp loads for epilogue (plain cached; overlap with the poll)
        const unsigned short* xpp = xp + (((long)t * 32 + ug) * 64 + b_own) * 96;
        float xr = bf2f(xpp[u_loc]);
        float xz = bf2f(xpp[32 + u_loc]);
        float xn = bf2f(xpp[64 + u_loc]);

        // ---- single-wave flag poll (1 dword/lane, no payload, no sleep) ----
        if (t > 0) {
            if (wv == 0) {
                const unsigned* fp = flags + mg * 32 + (lane & 31);
                for (;;) {
                    unsigned fv;
                    asm volatile("global_load_dword %0, %1, off sc0 sc1\n\ts_waitcnt vmcnt(0)"
                                 : "=v"(fv) : "v"(fp) : "memory");
                    if (__all(fv >= (unsigned)t)) break;
                }
            }
            __syncthreads();  // release all waves
        }

        // ---- h chunk load, exactly once: 4 x dwordx4 = 64B/lane ----
        const unsigned short* hp = hring + ((slot_r * NB + m0 + l16) * NH + kc0 + lq * 8);
        bf16x8 av[4];
        asm volatile(
            "global_load_dwordx4 %0, %4, off sc0 sc1\n\t"
            "global_load_dwordx4 %1, %4, off offset:64 sc0 sc1\n\t"
            "global_load_dwordx4 %2, %4, off offset:128 sc0 sc1\n\t"
            "global_load_dwordx4 %3, %4, off offset:192 sc0 sc1\n\t"
            "s_waitcnt vmcnt(0)"
            : "=&v"(av[0]), "=&v"(av[1]), "=&v"(av[2]), "=&v"(av[3])
            : "v"(hp) : "memory");

        f32x4 acc[2][3];
#pragma unroll
        for (int f = 0; f < 2; ++f)
#pragma unroll
            for (int g = 0; g < 3; ++g) acc[f][g] = (f32x4){0.f, 0.f, 0.f, 0.f};
#pragma unroll
        for (int ks = 0; ks < 4; ++ks)
#pragma unroll
            for (int f = 0; f < 2; ++f)
#pragma unroll
                for (int g = 0; g < 3; ++g)
                    acc[f][g] = mfma16(av[ks], Bf[g][f][ks], acc[f][g]);

#pragma unroll
        for (int f = 0; f < 2; ++f)
#pragma unroll
            for (int g = 0; g < 3; ++g) red[wv][f * 3 + g][lane] = acc[f][g];
        __syncthreads();

        float pre[3];
#pragma unroll
        for (int g = 0; g < 3; ++g) {
            float s = 0.0f;
#pragma unroll
            for (int w = 0; w < 8; ++w) s += red[w][shalf + g][lane_t][i_t];
            pre[g] = s + bh[g];
        }

        float r = 1.0f / (1.0f + __expf(-(xr + pre[0])));
        float z = 1.0f / (1.0f + __expf(-(xz + pre[1])));
        float narg = xn + r * pre[2];
        float nval = 1.0f - 2.0f / (__expf(2.0f * narg) + 1.0f);  // tanh
        float hnew = (1.0f - z) * nval + z * hf;
        hf = hnew;

        // h store (sc0 sc1) -> drain -> barrier -> flag; out store off-path
        {
            unsigned short* hw = hring + (slot_w * NB + b_own) * NH + u_own;
            unsigned hv = (unsigned)f2bf(hnew);
            asm volatile("global_store_short %0, %1, off sc0 sc1"
                         :: "v"(hw), "v"(hv) : "memory");
        }
        asm volatile("s_waitcnt vmcnt(0)" ::: "memory");  // h visible at coherent point
        __syncthreads();                                   // all waves drained
        if (tid == 0) {
            unsigned fv = (unsigned)(t + 1);
            asm volatile("global_store_dword %0, %1, off sc0 sc1"
                         :: "v"(flags + mg * 32 + ug), "v"(fv) : "memory");
        }
        out[((long)b_own * NT + t) * NH + u_own] = hnew;
    }
}

extern "C" void kernel_launch(void* const* d_in, const int* in_sizes, int n_in,
                              void* d_out, int out_size, void* d_ws, size_t ws_size,
                              hipStream_t stream) {
    const float* enc = (const float*)d_in[0];
    const float* Wih = (const float*)d_in[1];
    const float* Whh = (const float*)d_in[2];
    const float* bih = (const float*)d_in[3];
    const float* bhh = (const float*)d_in[4];
    float* out = (float*)d_out;

    // workspace carve
    char* p = (char*)d_ws;
    unsigned short* enc_t = (unsigned short*)p; p += (size_t)NT * NB * NH * 2;   // 64 MB
    unsigned short* xp    = (unsigned short*)p; p += (size_t)NT * NB * NG * 2;   // 192 MB
    unsigned short* wih_b = (unsigned short*)p; p += (size_t)NG * NH * 2;        // 6 MB
    unsigned short* whh_b = (unsigned short*)p; p += (size_t)NG * NH * 2;        // 6 MB
    size_t need = (size_t)(p - (char*)d_ws);

    // sync region aliases dead enc_t: [hring 4*64*1024 bf16][flags 128 u32]
    unsigned short* hring = enc_t;
    unsigned* flags = (unsigned*)(hring + (size_t)4 * NB * NH);

    if (ws_size < need) {
        long n = (long)out_size;
        k_fill_sentinel<<<(int)((n + 255) / 256), 256, 0, stream>>>(out, n);
        return;
    }

    // Phase 0: conversions
    {
        int n = NG * NH;  // 3145728
        k_convert<<<(n + 255) / 256, 256, 0, stream>>>(Wih, wih_b, n);
        k_convert<<<(n + 255) / 256, 256, 0, stream>>>(Whh, whh_b, n);
        long ne = (long)NB * NT * NH;
        k_convert_enc<<<(int)((ne + 255) / 256), 256, 0, stream>>>(enc, enc_t);
    }

    // Phase 1: x_proj GEMM (reads enc_t)
    {
        dim3 grid(NG / 128, (NT * NB) / 128);  // (24, 256)
        k_xproj<<<grid, 256, 0, stream>>>(enc_t, wih_b, bih, xp);
    }

    // Phase 1.5: zero sync region (after enc_t is dead)
    k_init_sync<<<(SYNC_WORDS + 255) / 256, 256, 0, stream>>>((unsigned*)hring);

    // Phase 2: one persistent scan kernel
    k_scan<<<128, 512, 0, stream>>>(whh_b, bhh, xp, hring, flags, out);
}

// Round 11
// 2289.840 us; speedup vs baseline: 6.8549x; 1.0074x over previous
//
#include <hip/hip_runtime.h>
#include <hip/hip_bf16.h>

// GRU decoder: B=64, T=512, H=1024
// Phase 0: convert enc -> bf16 [T,B,H], W_ih/W_hh -> bf16
// Phase 1: x_proj GEMM, m97-style (128x128 tile, BK=32, global_load_lds)
// Phase 1.5: zero h ring + flags (aliases dead enc_t region)
// Phase 2: persistent scan, 128 blocks x 512 thr, 4 batch-groups x 32 unit-blocks.
//   PER-WAVE decoupled protocol: wave wv's K-chunk [wv*128,+128) is produced by
//   exactly 4 ublocks (wv*4..+3); each wave polls only those 4 flags then
//   immediately loads h + runs its MFMAs. Block-wide coupling only at the LDS
//   reduce. Producer: h store (sc0sc1) -> vmcnt(0) -> barrier -> tid0 flag.
//   Ring depth 4; WAR proof: block's h-store is behind the reduce barrier whose
//   per-wave poll union = all 32 group blocks >= t.

typedef short bf16x8 __attribute__((ext_vector_type(8)));
typedef float f32x4 __attribute__((ext_vector_type(4)));

#define NB 64
#define NT 512
#define NH 1024
#define NG 3072           // 3*NH

static __device__ __forceinline__ float bf2f(unsigned short u) {
    unsigned int x = ((unsigned int)u) << 16;
    float f;
    __builtin_memcpy(&f, &x, sizeof(f));
    return f;
}
static __device__ __forceinline__ unsigned short f2bf(float f) {
    unsigned int x;
    __builtin_memcpy(&x, &f, sizeof(x));
    x += 0x7fffu + ((x >> 16) & 1u);  // round-to-nearest-even
    return (unsigned short)(x >> 16);
}

static __device__ __forceinline__ f32x4 mfma16(bf16x8 a, bf16x8 b, f32x4 c) {
    return __builtin_amdgcn_mfma_f32_16x16x32_bf16(a, b, c, 0, 0, 0);
}

// async global->LDS, 16B per lane; LDS dest = wave-uniform base + lane*16
#define GLD16(gp, lp) __builtin_amdgcn_global_load_lds( \
    (const __attribute__((address_space(1))) void*)(gp), \
    (__attribute__((address_space(3))) void*)(lp), 16, 0, 0)

__global__ void k_fill_sentinel(float* __restrict__ o, long n) {
    long i = (long)blockIdx.x * blockDim.x + threadIdx.x;
    if (i < n) o[i] = 12345.0f;
}

__global__ void k_convert(const float* __restrict__ in, unsigned short* __restrict__ o, int n) {
    int i = blockIdx.x * blockDim.x + threadIdx.x;
    if (i < n) o[i] = f2bf(in[i]);
}

// enc [B,T,H] f32 -> enc_t [T,B,H] bf16
__global__ void k_convert_enc(const float* __restrict__ enc, unsigned short* __restrict__ o) {
    long i = (long)blockIdx.x * blockDim.x + threadIdx.x;
    if (i >= (long)NB * NT * NH) return;
    int h = (int)(i % NH);
    long bt = i / NH;
    int t = (int)(bt % NT);
    int b = (int)(bt / NT);
    o[((long)t * NB + b) * NH + h] = f2bf(enc[i]);
}

// zero h ring (4*64*1024 bf16 = 131072 u32) + flags (128 u32)
#define SYNC_WORDS (4 * NB * NH / 2 + 128)
__global__ void k_init_sync(unsigned int* __restrict__ base) {
    int i = blockIdx.x * blockDim.x + threadIdx.x;
    if (i < SYNC_WORDS) base[i] = 0u;
}

// Phase 1 GEMM, m97 structure (unchanged from round 10).
__global__ __launch_bounds__(256) void k_xproj(
    const unsigned short* __restrict__ X,   // [M, K] bf16
    const unsigned short* __restrict__ W,   // [N, K] bf16
    const float* __restrict__ bias,         // [N]
    unsigned short* __restrict__ xp)        // [T][32][64][96] bf16
{
    __shared__ unsigned short As[128 * 32];
    __shared__ unsigned short Bs[128 * 32];

    const int tid  = threadIdx.x;
    const int lane = tid & 63;
    const int wv   = tid >> 6;
    const int l16  = lane & 15;
    const int lq   = lane >> 4;
    const int wr   = wv >> 1;
    const int wc   = wv & 1;
    const int n0   = blockIdx.x * 128;
    const int m0   = blockIdx.y * 128;

    f32x4 acc[4][4];
#pragma unroll
    for (int mi = 0; mi < 4; ++mi)
#pragma unroll
        for (int nj = 0; nj < 4; ++nj) acc[mi][nj] = (f32x4){0.f, 0.f, 0.f, 0.f};

    const int r0 = tid >> 2;
    const int c0e = (tid & 3) * 8;
    const int r1 = (256 + tid) >> 2;

    for (int k0 = 0; k0 < NH; k0 += 32) {
        GLD16(X + (size_t)(m0 + r0) * NH + k0 + c0e, &As[tid * 8]);
        GLD16(X + (size_t)(m0 + r1) * NH + k0 + c0e, &As[(256 + tid) * 8]);
        GLD16(W + (size_t)(n0 + r0) * NH + k0 + c0e, &Bs[tid * 8]);
        GLD16(W + (size_t)(n0 + r1) * NH + k0 + c0e, &Bs[(256 + tid) * 8]);
        __syncthreads();

        bf16x8 a[4], b[4];
#pragma unroll
        for (int mi = 0; mi < 4; ++mi)
            a[mi] = *(const bf16x8*)&As[(wr * 64 + mi * 16 + l16) * 32 + lq * 8];
#pragma unroll
        for (int nj = 0; nj < 4; ++nj)
            b[nj] = *(const bf16x8*)&Bs[(wc * 64 + nj * 16 + l16) * 32 + lq * 8];
#pragma unroll
        for (int mi = 0; mi < 4; ++mi)
#pragma unroll
            for (int nj = 0; nj < 4; ++nj)
                acc[mi][nj] = mfma16(a[mi], b[nj], acc[mi][nj]);
        __syncthreads();
    }

#pragma unroll
    for (int nj = 0; nj < 4; ++nj) {
        int n = n0 + wc * 64 + nj * 16 + l16;
        float bv = bias[n];
        int g   = n >> 10;
        int u   = n & 1023;
        int ugb = u >> 5;
        int ui  = u & 31;
#pragma unroll
        for (int mi = 0; mi < 4; ++mi) {
#pragma unroll
            for (int i = 0; i < 4; ++i) {
                int m = m0 + wr * 64 + mi * 16 + lq * 4 + i;
                int t = m >> 6;
                int b = m & 63;
                xp[(((long)t * 32 + ugb) * 64 + b) * 96 + g * 32 + ui] = f2bf(acc[mi][nj][i] + bv);
            }
        }
    }
}

// Phase 2: persistent scan, per-wave decoupled flag protocol.
// Grid 128 = mg(4) x ug(32). Block 512 thr = 8 waves.
// Block owns batches m0..m0+15, units u0..u0+31 (96 Whh rows pinned in regs).
// Wave wv handles K-chunk [wv*128, +128), produced by ublocks wv*4..wv*4+3.
__global__ __launch_bounds__(512, 1) void k_scan(
    const unsigned short* __restrict__ Whh,   // [3H, H] bf16
    const float* __restrict__ bhh,            // [3H]
    const unsigned short* __restrict__ xp,    // [T][32][64][96] bf16
    unsigned short* __restrict__ hring,       // [4][64][1024] bf16
    unsigned* __restrict__ flags,             // [128] = [mg*32+ug]
    float* __restrict__ out)                  // [B, T, H] f32
{
    const int tid  = threadIdx.x;
    const int lane = tid & 63;
    const int wv   = tid >> 6;        // 0..7
    const int l16  = lane & 15;
    const int lq   = lane >> 4;
    const int bid  = blockIdx.x;
    const int mg   = bid >> 5;        // 0..3
    const int ug   = bid & 31;        // 0..31
    const int m0   = mg * 16;
    const int u0   = ug * 32;
    const int kc0  = wv * 128;

    // Whh slice as MFMA B-fragments, pinned for the whole scan.
    bf16x8 Bf[3][2][4];
#pragma unroll
    for (int g = 0; g < 3; ++g)
#pragma unroll
        for (int f = 0; f < 2; ++f)
#pragma unroll
            for (int ks = 0; ks < 4; ++ks)
                Bf[g][f][ks] = *(const bf16x8*)(Whh + (long)(g * NH + u0 + f * 16 + l16) * NH + kc0 + ks * 32 + lq * 8);
#pragma unroll
    for (int g = 0; g < 3; ++g)
#pragma unroll
        for (int f = 0; f < 2; ++f)
#pragma unroll
            for (int ks = 0; ks < 4; ++ks)
                asm volatile("" : "+v"(Bf[g][f][ks]));  // forbid rematerialization

    // epilogue ownership: 1 output (b_own, u_own) per thread
    const int u_loc = tid & 31;
    const int b_loc = tid >> 5;       // 0..15
    const int b_own = m0 + b_loc;
    const int u_own = u0 + u_loc;
    float bh[3];
#pragma unroll
    for (int g = 0; g < 3; ++g) bh[g] = bhh[g * NH + u_own];
    float hf = 0.0f;                  // fp32 h for (b_own,u_own), in-register

    // C-frag element holding (b_loc, u_loc&15)
    const int lane_t = (b_loc >> 2) * 16 + (u_loc & 15);
    const int i_t    = b_loc & 3;
    const int shalf  = (u_loc >> 4) * 3;   // frag-slot base: 0 or 3

    // this wave's 4 producer flags (K-chunk kc0..kc0+128 = ublocks wv*4..+3)
    const unsigned* fp_my = flags + mg * 32 + wv * 4 + (lane & 3);

    __shared__ f32x4 red[8][6][64];   // 48 KB

    for (int t = 0; t < NT; ++t) {
        const int slot_r = (t + 3) & 3;
        const int slot_w = t & 3;

        // xp loads for epilogue (plain cached; overlap with the poll)
        const unsigned short* xpp = xp + (((long)t * 32 + ug) * 64 + b_own) * 96;
        float xr = bf2f(xpp[u_loc]);
        float xz = bf2f(xpp[32 + u_loc]);
        float xn = bf2f(xpp[64 + u_loc]);

        // ---- per-wave poll: only THIS wave's 4 producers (4 UC dwords) ----
        if (t > 0) {
            for (;;) {
                unsigned fv;
                asm volatile("global_load_dword %0, %1, off sc0 sc1\n\ts_waitcnt vmcnt(0)"
                             : "=v"(fv) : "v"(fp_my) : "memory");
                if (__all(fv >= (unsigned)t)) break;
            }
        }

        // ---- h chunk load, exactly once: 4 x dwordx4 = 64B/lane ----
        const unsigned short* hp = hring + ((slot_r * NB + m0 + l16) * NH + kc0 + lq * 8);
        bf16x8 av[4];
        asm volatile(
            "global_load_dwordx4 %0, %4, off sc0 sc1\n\t"
            "global_load_dwordx4 %1, %4, off offset:64 sc0 sc1\n\t"
            "global_load_dwordx4 %2, %4, off offset:128 sc0 sc1\n\t"
            "global_load_dwordx4 %3, %4, off offset:192 sc0 sc1\n\t"
            "s_waitcnt vmcnt(0)"
            : "=&v"(av[0]), "=&v"(av[1]), "=&v"(av[2]), "=&v"(av[3])
            : "v"(hp) : "memory");

        f32x4 acc[2][3];
#pragma unroll
        for (int f = 0; f < 2; ++f)
#pragma unroll
            for (int g = 0; g < 3; ++g) acc[f][g] = (f32x4){0.f, 0.f, 0.f, 0.f};
#pragma unroll
        for (int ks = 0; ks < 4; ++ks)
#pragma unroll
            for (int f = 0; f < 2; ++f)
#pragma unroll
                for (int g = 0; g < 3; ++g)
                    acc[f][g] = mfma16(av[ks], Bf[g][f][ks], acc[f][g]);

#pragma unroll
        for (int f = 0; f < 2; ++f)
#pragma unroll
            for (int g = 0; g < 3; ++g) red[wv][f * 3 + g][lane] = acc[f][g];
        __syncthreads();  // all waves' partials in LDS (union of polls = 32 blocks >= t)

        float pre[3];
#pragma unroll
        for (int g = 0; g < 3; ++g) {
            float s = 0.0f;
#pragma unroll
            for (int w = 0; w < 8; ++w) s += red[w][shalf + g][lane_t][i_t];
            pre[g] = s + bh[g];
        }

        float r = 1.0f / (1.0f + __expf(-(xr + pre[0])));
        float z = 1.0f / (1.0f + __expf(-(xz + pre[1])));
        float narg = xn + r * pre[2];
        float nval = 1.0f - 2.0f / (__expf(2.0f * narg) + 1.0f);  // tanh
        float hnew = (1.0f - z) * nval + z * hf;
        hf = hnew;

        // h store (sc0 sc1) -> drain -> barrier (also guards red[]) -> flag
        {
            unsigned short* hw = hring + (slot_w * NB + b_own) * NH + u_own;
            unsigned hv = (unsigned)f2bf(hnew);
            asm volatile("global_store_short %0, %1, off sc0 sc1"
                         :: "v"(hw), "v"(hv) : "memory");
        }
        asm volatile("s_waitcnt vmcnt(0)" ::: "memory");  // h visible at coherent point
        __syncthreads();                                   // all waves drained + red[] free
        if (tid == 0) {
            unsigned fv = (unsigned)(t + 1);
            asm volatile("global_store_dword %0, %1, off sc0 sc1"
                         :: "v"(flags + mg * 32 + ug), "v"(fv) : "memory");
        }
        out[((long)b_own * NT + t) * NH + u_own] = hnew;
    }
}

extern "C" void kernel_launch(void* const* d_in, const int* in_sizes, int n_in,
                              void* d_out, int out_size, void* d_ws, size_t ws_size,
                              hipStream_t stream) {
    const float* enc = (const float*)d_in[0];
    const float* Wih = (const float*)d_in[1];
    const float* Whh = (const float*)d_in[2];
    const float* bih = (const float*)d_in[3];
    const float* bhh = (const float*)d_in[4];
    float* out = (float*)d_out;

    // workspace carve
    char* p = (char*)d_ws;
    unsigned short* enc_t = (unsigned short*)p; p += (size_t)NT * NB * NH * 2;   // 64 MB
    unsigned short* xp    = (unsigned short*)p; p += (size_t)NT * NB * NG * 2;   // 192 MB
    unsigned short* wih_b = (unsigned short*)p; p += (size_t)NG * NH * 2;        // 6 MB
    unsigned short* whh_b = (unsigned short*)p; p += (size_t)NG * NH * 2;        // 6 MB
    size_t need = (size_t)(p - (char*)d_ws);

    // sync region aliases dead enc_t: [hring 4*64*1024 bf16][flags 128 u32]
    unsigned short* hring = enc_t;
    unsigned* flags = (unsigned*)(hring + (size_t)4 * NB * NH);

    if (ws_size < need) {
        long n = (long)out_size;
        k_fill_sentinel<<<(int)((n + 255) / 256), 256, 0, stream>>>(out, n);
        return;
    }

    // Phase 0: conversions
    {
        int n = NG * NH;  // 3145728
        k_convert<<<(n + 255) / 256, 256, 0, stream>>>(Wih, wih_b, n);
        k_convert<<<(n + 255) / 256, 256, 0, stream>>>(Whh, whh_b, n);
        long ne = (long)NB * NT * NH;
        k_convert_enc<<<(int)((ne + 255) / 256), 256, 0, stream>>>(enc, enc_t);
    }

    // Phase 1: x_proj GEMM (reads enc_t)
    {
        dim3 grid(NG / 128, (NT * NB) / 128);  // (24, 256)
        k_xproj<<<grid, 256, 0, stream>>>(enc_t, wih_b, bih, xp);
    }

    // Phase 1.5: zero sync region (after enc_t is dead)
    k_init_sync<<<(SYNC_WORDS + 255) / 256, 256, 0, stream>>>((unsigned*)hring);

    // Phase 2: one persistent scan kernel
    k_scan<<<128, 512, 0, stream>>>(whh_b, bhh, xp, hring, flags, out);
}